// Round 3
// baseline (1450.636 us; speedup 1.0000x reference)
//
#include <hip/hip_runtime.h>

// AutoformerAttention on MI355X.
// Pipeline:
//   At = Wk @ Wq^T (split-bf16 MFMA, limbs written directly from acc)
//   P  = hs @ At   (split-bf16 MFMA, stored transposed [B,E,T])   } fused in one
//   V  = hs @ Wv + bv (bf16 MFMA)                                 } launch (k_gemm_pv)
//   S[b,pair] = sum_e Pf * conj(HSf) via packed complex FFT (z = P + i*hs) per (b,e),
//     computed in the bit-reversed domain (pair q = 3*2^k-1-p), stride-1 unpack.
//   mean_ac = DIT-FFT(conj(S)) /(T*E) + const/E; top-24 fused in the same kernel.
//   agg[b,t,e] = sum_k w[h%8,k] * V[b,(t+d)%T,e]  -> out = agg @ Wo + bo
// hs is read ONCE (k_prep_hs: split limbs + hsT + Sq/Sk partials fused).
// Workspace ~470 MB; agg aliases hs_hi (dead after the P/V GEMMs).

typedef unsigned short u16;
typedef __attribute__((ext_vector_type(8))) short short8_t;
typedef __attribute__((ext_vector_type(4))) float float4_t;

struct cplx { float x, y; };
struct __align__(8) u16x4 { u16 x, y, z, w; };

#define DEVINL static __device__ __forceinline__

DEVINL u16 bf_from_f(float x){
  unsigned u = __float_as_uint(x);
  u += 0x7fffu + ((u >> 16) & 1u);
  return (u16)(u >> 16);
}
DEVINL float f_from_bf(u16 h){ return __uint_as_float(((unsigned)h) << 16); }

typedef const void __attribute__((address_space(1)))* gas_ptr;
typedef void __attribute__((address_space(3)))* las_ptr;
DEVINL void async16(const void* g, void* l){
  __builtin_amdgcn_global_load_lds((gas_ptr)g, (las_ptr)l, 16, 0, 0);
}

// ---------------- weight prep ----------------

// split Wq and Wk into bf16 limbs in one launch (blocks 0..1023: Wq, 1024..2047: Wk)
__global__ void k_split2(const float* __restrict__ Wq, const float* __restrict__ Wk,
                         u16* __restrict__ Qh, u16* __restrict__ Ql,
                         u16* __restrict__ Kh, u16* __restrict__ Kl){
  int isK = blockIdx.x >> 10;
  int i = (blockIdx.x & 1023) * 256 + threadIdx.x;   // < 262144
  const float* src = isK ? Wk : Wq;
  u16* ph = isK ? Kh : Qh;
  u16* pl = isK ? Kl : Ql;
  float4 v = ((const float4*)src)[i];
  u16x4 h, l;
  h.x = bf_from_f(v.x); l.x = bf_from_f(v.x - f_from_bf(h.x));
  h.y = bf_from_f(v.y); l.y = bf_from_f(v.y - f_from_bf(h.y));
  h.z = bf_from_f(v.z); l.z = bf_from_f(v.z - f_from_bf(h.z));
  h.w = bf_from_f(v.w); l.w = bf_from_f(v.w - f_from_bf(h.w));
  ((u16x4*)ph)[i] = h; ((u16x4*)pl)[i] = l;
}

// WT[n][k] = bf16(W[k][n]) for Wv (z=0) and Wo (z=1), 1024x1024
__global__ void k_transpose2_bf16(const float* __restrict__ Wv, const float* __restrict__ Wo,
                                  u16* __restrict__ WvT, u16* __restrict__ WoT){
  __shared__ float tile[32][33];
  const float* W = blockIdx.z ? Wo : Wv;
  u16* WT = blockIdx.z ? WoT : WvT;
  int k0 = blockIdx.x * 32, n0 = blockIdx.y * 32;
  int x = threadIdx.x, y0 = threadIdx.y;
  for (int j = y0; j < 32; j += 8) tile[j][x] = W[(size_t)(k0 + j) * 1024 + n0 + x];
  __syncthreads();
  for (int j = y0; j < 32; j += 8) WT[(size_t)(n0 + j) * 1024 + k0 + x] = bf_from_f(tile[x][j]);
}

// u[t] = Wq[t,:].bk ; w2[i] = Wk[i,:].bq ; c0 = bq.bk ; also zero Sq/Sk.
// One wave per row, shuffle reduce.
__global__ __launch_bounds__(256) void k_uvc(const float* __restrict__ Wq,
    const float* __restrict__ Wk, const float* __restrict__ bq, const float* __restrict__ bk,
    float* __restrict__ u, float* __restrict__ w2, float* __restrict__ c0,
    float* __restrict__ Sq, float* __restrict__ Sk){
  int gw = blockIdx.x * 4 + (threadIdx.x >> 6);
  int lane = threadIdx.x & 63;
  if (gw < 2048){
    const float* row = (gw < 1024) ? (Wq + (size_t)gw * 1024) : (Wk + (size_t)(gw - 1024) * 1024);
    const float* vec = (gw < 1024) ? bk : bq;
    float s = 0;
    for (int m = lane; m < 1024; m += 64) s += row[m] * vec[m];
    for (int o = 32; o; o >>= 1) s += __shfl_down(s, o);
    if (lane == 0){ if (gw < 1024) u[gw] = s; else w2[gw - 1024] = s; }
  } else if (gw == 2048){
    float s = 0;
    for (int m = lane; m < 1024; m += 64) s += bq[m] * bk[m];
    for (int o = 32; o; o >>= 1) s += __shfl_down(s, o);
    if (lane == 0) c0[0] = s;
  } else if (gw == 2049){
    if (lane < 8){ Sq[lane] = 0.f; Sk[lane] = 0.f; }
  }
}

// ---------------- hs prep: ONE pass over hs ----------------
// per 32x32 (t,e) tile: write hs_hi/hs_lo [B,T,E], hsT [B,E,T] fp32,
// and accumulate Sq/Sk partials (hs . u / hs . w2 over the tile).
__global__ __launch_bounds__(256) void k_prep_hs(const float* __restrict__ hs,
    u16* __restrict__ hi, u16* __restrict__ lo, float* __restrict__ hsT,
    const float* __restrict__ uu, const float* __restrict__ w2,
    float* __restrict__ Sq, float* __restrict__ Sk){
  __shared__ float tile[32][33];
  __shared__ float r1[256], r2[256];
  int b = blockIdx.z, t0 = blockIdx.x * 32, e0 = blockIdx.y * 32;
  int x = threadIdx.x, y0 = threadIdx.y;
  int tid = threadIdx.y * 32 + x;
  const float* ib = hs + (size_t)b * 4194304;
  float ue = uu[e0 + x], we = w2[e0 + x];
  float a1 = 0, a2 = 0;
  for (int j = y0; j < 32; j += 8){
    float v = ib[(size_t)(t0 + j) * 1024 + e0 + x];
    tile[j][x] = v;
    a1 += v * ue; a2 += v * we;
  }
  r1[tid] = a1; r2[tid] = a2;
  __syncthreads();
  // hsT (coalesced in t)
  float* ob = hsT + (size_t)b * 4194304;
  for (int j = y0; j < 32; j += 8) ob[(size_t)(e0 + j) * 4096 + t0 + x] = tile[x][j];
  // split limbs, 4 e per thread (8 B stores)
  {
    int jj = tid >> 3, cc = (tid & 7) * 4;
    float v0 = tile[jj][cc], v1 = tile[jj][cc + 1], v2 = tile[jj][cc + 2], v3 = tile[jj][cc + 3];
    u16x4 h, l;
    h.x = bf_from_f(v0); l.x = bf_from_f(v0 - f_from_bf(h.x));
    h.y = bf_from_f(v1); l.y = bf_from_f(v1 - f_from_bf(h.y));
    h.z = bf_from_f(v2); l.z = bf_from_f(v2 - f_from_bf(h.z));
    h.w = bf_from_f(v3); l.w = bf_from_f(v3 - f_from_bf(h.w));
    size_t off = (size_t)b * 4194304 + (size_t)(t0 + jj) * 1024 + e0 + cc;
    *(u16x4*)(hi + off) = h; *(u16x4*)(lo + off) = l;
  }
  // Sq/Sk reduce
  for (int s = 128; s; s >>= 1){
    if (tid < s){ r1[tid] += r1[tid + s]; r2[tid] += r2[tid + s]; }
    __syncthreads();
  }
  if (tid == 0){ atomicAdd(&Sq[b], r1[0]); atomicAdd(&Sk[b], r2[0]); }
}

// ---------------- GEMM (128x128 tile, 16x16x32 bf16 MFMA) ----------------
// A: [M,K] row-major bf16 (limbs). B: [N,K] row-major (i.e. math-B transposed).
// MODE 0: fp32 [M,N]; 1: P_t layout fp32 (b=n>>12, addr b*4M + m*4096 + (n&4095));
// MODE 2: bf16 [M,N] + bias[n]; 3: fp32 [M,N] + bias[n];
// MODE 4: split-bf16 limbs (outB=hi, outB2=lo), no bias.

DEVINL void stage_tile(const u16* __restrict__ src, int ld, int row0, int kb,
                       u16* lds, int wave, int lane){
  int r = lane >> 2, c = lane & 3;
  #pragma unroll
  for (int is = wave; is < 8; is += 4){
    const u16* g = src + (size_t)(row0 + is * 16 + r) * ld + kb + c * 8;
    async16((const void*)g, (void*)(lds + is * 512));  // lds base wave-uniform, lane*16B linear
  }
}

template<int SPLIT, int MODE>
DEVINL void gemm_body(const u16* __restrict__ Ah, const u16* __restrict__ Al,
                      const u16* __restrict__ Bh, const u16* __restrict__ Bl,
                      float* __restrict__ outF, u16* __restrict__ outB, u16* __restrict__ outB2,
                      const float* __restrict__ bias, int M, int N, int K,
                      int m0, int n0, u16* sAh, u16* sBh, u16* sAl, u16* sBl)
{
  int tid = threadIdx.x, wave = tid >> 6, lane = tid & 63;
  int wm = wave >> 1, wn = wave & 1;
  float4_t zero = {0.0f, 0.0f, 0.0f, 0.0f};
  float4_t acc[4][4];
  #pragma unroll
  for (int i = 0; i < 4; i++)
    #pragma unroll
    for (int j = 0; j < 4; j++) acc[i][j] = zero;

  int ar = wm * 64 + (lane & 15);
  int bc = wn * 64 + (lane & 15);
  int kq = (lane >> 4) * 8;

  for (int kb = 0; kb < K; kb += 32){
    stage_tile(Ah, K, m0, kb, sAh, wave, lane);
    stage_tile(Bh, K, n0, kb, sBh, wave, lane);
    if (SPLIT){
      stage_tile(Al, K, m0, kb, sAl, wave, lane);
      stage_tile(Bl, K, n0, kb, sBl, wave, lane);
    }
    __syncthreads();
    short8_t af[4], bfr[4], afl[4], bfl[4];
    #pragma unroll
    for (int i = 0; i < 4; i++){
      af[i]  = *(const short8_t*)(sAh + (ar + i * 16) * 32 + kq);
      bfr[i] = *(const short8_t*)(sBh + (bc + i * 16) * 32 + kq);
      if (SPLIT){
        afl[i] = *(const short8_t*)(sAl + (ar + i * 16) * 32 + kq);
        bfl[i] = *(const short8_t*)(sBl + (bc + i * 16) * 32 + kq);
      }
    }
    #pragma unroll
    for (int mi = 0; mi < 4; mi++)
      #pragma unroll
      for (int ni = 0; ni < 4; ni++){
        acc[mi][ni] = __builtin_amdgcn_mfma_f32_16x16x32_bf16(af[mi], bfr[ni], acc[mi][ni], 0, 0, 0);
        if (SPLIT){
          acc[mi][ni] = __builtin_amdgcn_mfma_f32_16x16x32_bf16(af[mi], bfl[ni], acc[mi][ni], 0, 0, 0);
          acc[mi][ni] = __builtin_amdgcn_mfma_f32_16x16x32_bf16(afl[mi], bfr[ni], acc[mi][ni], 0, 0, 0);
        }
      }
    __syncthreads();
  }

  int col = lane & 15, rq = lane >> 4;
  #pragma unroll
  for (int mi = 0; mi < 4; mi++)
    #pragma unroll
    for (int ni = 0; ni < 4; ni++){
      int gm = m0 + wm * 64 + mi * 16 + rq * 4;
      int gn = n0 + wn * 64 + ni * 16 + col;
      float4_t v = acc[mi][ni];
      #pragma unroll
      for (int r = 0; r < 4; r++){
        int row = gm + r;
        if (MODE == 0){
          outF[(size_t)row * N + gn] = v[r];
        } else if (MODE == 1){
          int bb = gn >> 12, t = gn & 4095;
          outF[(size_t)bb * 4194304 + (size_t)row * 4096 + t] = v[r];
        } else if (MODE == 2){
          outB[(size_t)row * N + gn] = bf_from_f(v[r] + bias[gn]);
        } else if (MODE == 3){
          outF[(size_t)row * N + gn] = v[r] + bias[gn];
        } else {
          float val = v[r];
          u16 h = bf_from_f(val);
          outB[(size_t)row * N + gn] = h;
          outB2[(size_t)row * N + gn] = bf_from_f(val - f_from_bf(h));
        }
      }
    }
}

template<int SPLIT, int MODE>
__global__ __launch_bounds__(256) void k_gemm128(
    const u16* __restrict__ Ah, const u16* __restrict__ Al,
    const u16* __restrict__ Bh, const u16* __restrict__ Bl,
    float* __restrict__ outF, u16* __restrict__ outB, u16* __restrict__ outB2,
    const float* __restrict__ bias, int M, int N, int K)
{
  __shared__ u16 sAh[128 * 32];
  __shared__ u16 sBh[128 * 32];
  __shared__ u16 sAl[SPLIT ? 128 * 32 : 8];
  __shared__ u16 sBl[SPLIT ? 128 * 32 : 8];
  gemm_body<SPLIT, MODE>(Ah, Al, Bh, Bl, outF, outB, outB2, bias, M, N, K,
                         blockIdx.y * 128, blockIdx.x * 128, sAh, sBh, sAl, sBl);
}

// P GEMM (blocks 0..2047, split, MODE 1) + V GEMM (blocks 2048..4095, MODE 2) in one launch.
__global__ __launch_bounds__(256) void k_gemm_pv(
    const u16* __restrict__ At_hi, const u16* __restrict__ At_lo,
    const u16* __restrict__ hs_hi, const u16* __restrict__ hs_lo,
    float* __restrict__ Pt, const u16* __restrict__ WvT, u16* __restrict__ Vb,
    const float* __restrict__ bv)
{
  __shared__ u16 smem[4 * 128 * 32];
  int bx = blockIdx.x;
  if (bx < 2048){
    gemm_body<1, 1>(At_hi, At_lo, hs_hi, hs_lo, Pt, nullptr, nullptr, nullptr,
                    1024, 32768, 1024, (bx >> 8) * 128, (bx & 255) * 128,
                    smem, smem + 4096, smem + 8192, smem + 12288);
  } else {
    int id = bx - 2048;
    gemm_body<0, 2>(hs_hi, nullptr, WvT, nullptr, nullptr, Vb, nullptr, bv,
                    32768, 1024, 1024, (id >> 3) * 128, (id & 7) * 128,
                    smem, smem + 4096, smem + 8192, smem + 12288);
  }
}

// ---------------- FFT forward (fused radix-4 DIF, SoA + pad, scrambled-domain unpack) ----

#define FPAD(i) ((i) + ((i) >> 3))

__global__ __launch_bounds__(256) void k_fft_fwd(const float* __restrict__ Pt,
                                                 const float* __restrict__ hsT,
                                                 float* __restrict__ S){
  __shared__ float zr[4608];
  __shared__ float zi[4608];
  int tid = threadIdx.x;
  int b = blockIdx.x >> 7;
  int ch0 = (blockIdx.x & 127) * 8;
  float Gre[8], Gim[8];
  #pragma unroll
  for (int j = 0; j < 8; ++j){ Gre[j] = 0.f; Gim[j] = 0.f; }
  float g0 = 0.f, g1 = 0.f;

  for (int c = 0; c < 8; ++c){
    __syncthreads();  // previous channel's unpack reads complete before overwrite
    size_t base = ((size_t)b * 1024 + ch0 + c) * 4096;
    for (int i = tid; i < 4096; i += 256){
      zr[FPAD(i)] = Pt[base + i];
      zi[FPAD(i)] = hsT[base + i];
    }
    // 6 fused radix-4 passes == 12 radix-2 DIF stages (identical math, bit-reversed out)
    for (int h = 1024; h >= 1; h >>= 2){
      __syncthreads();
      float wsc = -3.14159265358979323846f / (float)(2 * h);
      for (int g = tid; g < 1024; g += 256){
        int lo = g & (h - 1);
        int i0 = ((g - lo) << 2) + lo;
        int j0 = FPAD(i0), j1 = FPAD(i0 + h), j2 = FPAD(i0 + 2 * h), j3 = FPAD(i0 + 3 * h);
        float x0 = zr[j0], y0 = zi[j0];
        float x1 = zr[j1], y1 = zi[j1];
        float x2 = zr[j2], y2 = zi[j2];
        float x3 = zr[j3], y3 = zi[j3];
        float s, co;
        __sincosf(wsc * (float)lo, &s, &co);
        float b0x = x0 + x2, b0y = y0 + y2;
        float t2x = x0 - x2, t2y = y0 - y2;
        float b2x = t2x * co - t2y * s, b2y = t2x * s + t2y * co;
        float b1x = x1 + x3, b1y = y1 + y3;
        float t3x = x1 - x3, t3y = y1 - y3;
        float b3x = t3x * s + t3y * co, b3y = t3y * s - t3x * co;
        float vc = co * co - s * s, vs = 2.0f * co * s;
        float d1x = b0x - b1x, d1y = b0y - b1y;
        float d3x = b2x - b3x, d3y = b2y - b3y;
        zr[j0] = b0x + b1x;            zi[j0] = b0y + b1y;
        zr[j1] = d1x * vc - d1y * vs;  zi[j1] = d1x * vs + d1y * vc;
        zr[j2] = b2x + b3x;            zi[j2] = b2y + b3y;
        zr[j3] = d3x * vc - d3y * vs;  zi[j3] = d3x * vs + d3y * vc;
      }
    }
    __syncthreads();
    // scrambled-domain Hermitian-pair unpack, G accumulated in registers.
    #pragma unroll
    for (int j = 0; j < 8; ++j){
      int idx = tid + (j << 8);
      if (idx < 2047){
        int m = idx + 1;
        int e = 31 - __clz(m);
        int p = m + (1 << e);
        int q = (3 << (e + 1)) - 1 - p;
        int ip = FPAD(p), iq = FPAD(q);
        float xa = zr[ip], ya = zi[ip];
        float xb = zr[iq], yb = zi[iq];
        Gre[j] += 0.5f * (xa * yb + ya * xb);
        Gim[j] += 0.25f * ((xa * xa + ya * ya) - (xb * xb + yb * yb));
      }
    }
    if (tid == 0){
      g0 += zr[0] * zi[0];
      g1 += zr[FPAD(1)] * zi[FPAD(1)];
    }
  }

  float* Sb = S + (size_t)b * 2049 * 2;
  #pragma unroll
  for (int j = 0; j < 8; ++j){
    int idx = tid + (j << 8);
    if (idx < 2047){
      atomicAdd(&Sb[(2 + idx) * 2], Gre[j]);
      atomicAdd(&Sb[(2 + idx) * 2 + 1], Gim[j]);
    }
  }
  if (tid == 0){ atomicAdd(&Sb[0], g0); atomicAdd(&Sb[2], g1); }
}

// inverse + top-k fused: mean_ac lives only in LDS.
__global__ __launch_bounds__(256) void k_fft_inv_topk(const float* __restrict__ S,
    const float* __restrict__ Sq, const float* __restrict__ Sk,
    const float* __restrict__ c0, float* __restrict__ tv, int* __restrict__ ti){
  __shared__ cplx z[4096];
  __shared__ float vals[4096];
  __shared__ float rv[256];
  __shared__ int ri[256];
  int b = blockIdx.x, tid = threadIdx.x;
  const float* Sb = S + (size_t)b * 2049 * 2;
  #pragma unroll
  for (int j = 0; j < 8; ++j){
    int idx = tid + (j << 8);
    if (idx < 2047){
      int m = idx + 1;
      int e = 31 - __clz(m);
      int p = m + (1 << e);
      int q = (3 << (e + 1)) - 1 - p;
      float re = Sb[(2 + idx) * 2], im = Sb[(2 + idx) * 2 + 1];
      z[p].x = re; z[p].y = -im;
      z[q].x = re; z[q].y = im;
    }
  }
  if (tid == 0){
    z[0].x = Sb[0]; z[0].y = -Sb[1];
    z[1].x = Sb[2]; z[1].y = -Sb[3];
  }
  // DIT radix-2: bit-reversed input -> natural output
  for (int d = 1; d <= 2048; d <<= 1){
    __syncthreads();
    for (int j = tid; j < 2048; j += 256){
      int lo = j & (d - 1);
      int i = ((j & ~(d - 1)) << 1) | lo;
      float ang = -3.14159265358979323846f * (float)lo / (float)d;
      float s, co;
      __sincosf(ang, &s, &co);
      cplx av = z[i], bv = z[i + d];
      float tx = bv.x * co - bv.y * s;
      float ty = bv.x * s + bv.y * co;
      z[i].x = av.x + tx;     z[i].y = av.y + ty;
      z[i + d].x = av.x - tx; z[i + d].y = av.y - ty;
    }
  }
  __syncthreads();
  float constv = (Sq[b] + Sk[b] + 4096.0f * c0[0]) * (1.0f / 1024.0f);
  for (int t = tid; t < 4096; t += 256)
    vals[t] = z[t].x * (1.0f / 4194304.0f) + constv;
  __syncthreads();
  // top-24
  for (int it = 0; it < 24; ++it){
    float best = -3.0e38f; int bi = 0x7fffffff;
    for (int i = tid; i < 4096; i += 256){
      float v = vals[i];
      if (v > best){ best = v; bi = i; }
    }
    rv[tid] = best; ri[tid] = bi;
    __syncthreads();
    for (int s = 128; s > 0; s >>= 1){
      if (tid < s){
        if (rv[tid + s] > rv[tid] || (rv[tid + s] == rv[tid] && ri[tid + s] < ri[tid])){
          rv[tid] = rv[tid + s]; ri[tid] = ri[tid + s];
        }
      }
      __syncthreads();
    }
    if (tid == 0){
      tv[b * 24 + it] = rv[0]; ti[b * 24 + it] = ri[0];
      vals[ri[0]] = -3.0e38f;
    }
    __syncthreads();
  }
}

// ---------------- aggregation: agg[b,t,e] = sum_k w[h%8,k] * V[b,(t+d)%T,e] ----------------
// flat grid, b = blockIdx.x & 7 (XCD affinity: each XCD touches only V[b] = 8 MB);
// 16 B loads; (w,d) pairs in registers; k-loop fully unrolled.

__global__ __launch_bounds__(256, 4) void k_aggregate(const u16* __restrict__ V,
    const float* __restrict__ tv, const int* __restrict__ ti, u16* __restrict__ agg){
  __shared__ float wv[8][24];
  __shared__ int dv[8][24];
  int tid = threadIdx.x;
  if (tid < 192){ int s = tid / 24, k = tid % 24; wv[s][k] = tv[tid]; dv[s][k] = ti[tid]; }
  __syncthreads();
  int flat = blockIdx.x;           // 2048 blocks
  int b = flat & 7;                // XCD affinity
  int t0 = (flat >> 3) * 16;
  int oct = tid & 127;             // which 8-element e-group
  int th = tid >> 7;               // t parity within the pair
  int e = oct * 8;
  int sb = (oct >> 3) & 7;         // h % 8 (h = e/64)
  const u16* Vbase = V + (size_t)b * 4194304 + e;
  u16* abase = agg + (size_t)b * 4194304 + e;

  float wk[24]; int dk[24];
  #pragma unroll
  for (int k = 0; k < 24; ++k){ wk[k] = wv[sb][k]; dk[k] = dv[sb][k]; }

  for (int tt = 0; tt < 8; ++tt){
    int t = t0 + tt * 2 + th;
    float a0 = 0, a1 = 0, a2 = 0, a3 = 0, a4 = 0, a5 = 0, a6 = 0, a7 = 0;
    #pragma unroll
    for (int k = 0; k < 24; ++k){
      int st = (t + dk[k]) & 4095;
      int4 vv = *(const int4*)(Vbase + (size_t)st * 1024);
      float w = wk[k];
      a0 += w * __uint_as_float(((unsigned)vv.x) << 16);
      a1 += w * __uint_as_float(((unsigned)vv.x) & 0xFFFF0000u);
      a2 += w * __uint_as_float(((unsigned)vv.y) << 16);
      a3 += w * __uint_as_float(((unsigned)vv.y) & 0xFFFF0000u);
      a4 += w * __uint_as_float(((unsigned)vv.z) << 16);
      a5 += w * __uint_as_float(((unsigned)vv.z) & 0xFFFF0000u);
      a6 += w * __uint_as_float(((unsigned)vv.w) << 16);
      a7 += w * __uint_as_float(((unsigned)vv.w) & 0xFFFF0000u);
    }
    int4 o;
    o.x = (int)((unsigned)bf_from_f(a0) | ((unsigned)bf_from_f(a1) << 16));
    o.y = (int)((unsigned)bf_from_f(a2) | ((unsigned)bf_from_f(a3) << 16));
    o.z = (int)((unsigned)bf_from_f(a4) | ((unsigned)bf_from_f(a5) << 16));
    o.w = (int)((unsigned)bf_from_f(a6) | ((unsigned)bf_from_f(a7) << 16));
    *(int4*)(abase + (size_t)t * 1024) = o;
  }
}

// ---------------- launch ----------------

extern "C" void kernel_launch(void* const* d_in, const int* in_sizes, int n_in,
                              void* d_out, int out_size, void* d_ws, size_t ws_size,
                              hipStream_t stream){
  const float* hs = (const float*)d_in[0];
  const float* Wq = (const float*)d_in[1];
  const float* bq = (const float*)d_in[2];
  const float* Wk = (const float*)d_in[3];
  const float* bk = (const float*)d_in[4];
  const float* Wv = (const float*)d_in[5];
  const float* bv = (const float*)d_in[6];
  const float* Wo = (const float*)d_in[7];
  const float* bo = (const float*)d_in[8];

  char* ws = (char*)d_ws;
  const size_t MB = 1024ull * 1024ull;
  u16* hs_hi = (u16*)(ws);                 // 64MB; reused as agg after P/V GEMMs
  u16* hs_lo = (u16*)(ws + 64 * MB);       // 64MB
  float* Pt  = (float*)(ws + 128 * MB);    // 128MB  [B,E,T]
  float* hsT = (float*)(ws + 256 * MB);    // 128MB  [B,E,T]
  u16* Vb    = (u16*)(ws + 384 * MB);      // 64MB bf16 [B,T,E]
  char* sm   = ws + 448 * MB;
  u16* Wq_hi = (u16*)(sm + 0 * MB);
  u16* Wq_lo = (u16*)(sm + 2 * MB);
  u16* Wk_hi = (u16*)(sm + 4 * MB);
  u16* Wk_lo = (u16*)(sm + 6 * MB);
  u16* WvT   = (u16*)(sm + 8 * MB);
  u16* WoT   = (u16*)(sm + 10 * MB);
  u16* At_hi = (u16*)(sm + 16 * MB);
  u16* At_lo = (u16*)(sm + 18 * MB);
  float* S   = (float*)(sm + 20 * MB);     // 8 x 2049 pair-slots x 2 floats
  float* uu  = (float*)(sm + 22 * MB);
  float* w2  = (float*)(sm + 22 * MB + 8192);
  float* c0  = (float*)(sm + 22 * MB + 16384);
  float* Sq  = (float*)(sm + 22 * MB + 16640);
  float* Sk  = (float*)(sm + 22 * MB + 16896);
  float* tv  = (float*)(sm + 22 * MB + 17152);
  int*   ti  = (int*)(sm + 22 * MB + 18176);
  u16* agg   = hs_hi;

  hipMemsetAsync(S, 0, 8 * 2049 * 2 * sizeof(float), stream);

  k_uvc<<<513, 256, 0, stream>>>(Wq, Wk, bq, bk, uu, w2, c0, Sq, Sk);
  k_split2<<<2048, 256, 0, stream>>>(Wq, Wk, Wq_hi, Wq_lo, Wk_hi, Wk_lo);
  k_transpose2_bf16<<<dim3(32, 32, 2), dim3(32, 8), 0, stream>>>(Wv, Wo, WvT, WoT);
  k_prep_hs<<<dim3(128, 32, 8), dim3(32, 8), 0, stream>>>(hs, hs_hi, hs_lo, hsT, uu, w2, Sq, Sk);

  // At[e,k] = sum_m Wk[e,m] * Wq[k,m], split-bf16, limbs written directly
  k_gemm128<1, 4><<<dim3(8, 8), 256, 0, stream>>>(Wk_hi, Wk_lo, Wq_hi, Wq_lo,
                                                  nullptr, At_hi, At_lo, nullptr, 1024, 1024, 1024);
  // P^T (split, MODE 1) + V (MODE 2) in one launch
  k_gemm_pv<<<4096, 256, 0, stream>>>(At_hi, At_lo, hs_hi, hs_lo, Pt, WvT, Vb, bv);

  k_fft_fwd<<<1024, 256, 0, stream>>>(Pt, hsT, S);
  k_fft_inv_topk<<<8, 256, 0, stream>>>(S, Sq, Sk, c0, tv, ti);
  k_aggregate<<<2048, 256, 0, stream>>>(Vb, tv, ti, agg);
  // out = agg @ Wo + bo (fp32 out)
  k_gemm128<0, 3><<<dim3(8, 256), 256, 0, stream>>>(agg, nullptr, WoT, nullptr,
                                                    (float*)d_out, nullptr, nullptr, bo, 32768, 1024, 1024);
}

// Round 5
// 1449.939 us; speedup vs baseline: 1.0005x; 1.0005x over previous
//
#include <hip/hip_runtime.h>

// AutoformerAttention on MI355X.
// Pipeline:
//   At = Wk @ Wq^T (split-bf16 MFMA, limbs written directly from acc)
//   P  = hs @ At   (split-bf16 MFMA, stored transposed [B,E,T])   } fused in one
//   V  = hs @ Wv + bv (bf16 MFMA)                                 } launch (k_gemm_pv)
//   S[b,pair] = sum_e Pf * conj(HSf) via packed complex FFT (z = P + i*hs) per (b,e),
//     computed in the bit-reversed domain (pair q = 3*2^k-1-p), stride-1 unpack.
//   mean_ac = DIT-FFT(conj(S)) /(T*E) + const/E; top-24 fused in the same kernel.
//   agg[b,t,e] = sum_k w[h%8,k] * V[b,(t+d)%T,e]  -> out = agg @ Wo + bo
// hs is read ONCE (k_prep_hs: split limbs + hsT + Sq/Sk partials fused, float4 ILP).
// Workspace ~470 MB; agg aliases hs_hi (dead after the P/V GEMMs).

typedef unsigned short u16;
typedef __attribute__((ext_vector_type(8))) short short8_t;
typedef __attribute__((ext_vector_type(4))) float float4_t;

struct cplx { float x, y; };
struct __align__(8) u16x4 { u16 x, y, z, w; };

#define DEVINL static __device__ __forceinline__

DEVINL u16 bf_from_f(float x){
  unsigned u = __float_as_uint(x);
  u += 0x7fffu + ((u >> 16) & 1u);
  return (u16)(u >> 16);
}
DEVINL float f_from_bf(u16 h){ return __uint_as_float(((unsigned)h) << 16); }

typedef const void __attribute__((address_space(1)))* gas_ptr;
typedef void __attribute__((address_space(3)))* las_ptr;
DEVINL void async16(const void* g, void* l){
  __builtin_amdgcn_global_load_lds((gas_ptr)g, (las_ptr)l, 16, 0, 0);
}

// ---------------- weight prep ----------------

// split Wq and Wk into bf16 limbs in one launch (blocks 0..1023: Wq, 1024..2047: Wk)
__global__ void k_split2(const float* __restrict__ Wq, const float* __restrict__ Wk,
                         u16* __restrict__ Qh, u16* __restrict__ Ql,
                         u16* __restrict__ Kh, u16* __restrict__ Kl){
  int isK = blockIdx.x >> 10;
  int i = (blockIdx.x & 1023) * 256 + threadIdx.x;   // < 262144
  const float* src = isK ? Wk : Wq;
  u16* ph = isK ? Kh : Qh;
  u16* pl = isK ? Kl : Ql;
  float4 v = ((const float4*)src)[i];
  u16x4 h, l;
  h.x = bf_from_f(v.x); l.x = bf_from_f(v.x - f_from_bf(h.x));
  h.y = bf_from_f(v.y); l.y = bf_from_f(v.y - f_from_bf(h.y));
  h.z = bf_from_f(v.z); l.z = bf_from_f(v.z - f_from_bf(h.z));
  h.w = bf_from_f(v.w); l.w = bf_from_f(v.w - f_from_bf(h.w));
  ((u16x4*)ph)[i] = h; ((u16x4*)pl)[i] = l;
}

// WT[n][k] = bf16(W[k][n]) for Wv (z=0) and Wo (z=1), 1024x1024
__global__ void k_transpose2_bf16(const float* __restrict__ Wv, const float* __restrict__ Wo,
                                  u16* __restrict__ WvT, u16* __restrict__ WoT){
  __shared__ float tile[32][33];
  const float* W = blockIdx.z ? Wo : Wv;
  u16* WT = blockIdx.z ? WoT : WvT;
  int k0 = blockIdx.x * 32, n0 = blockIdx.y * 32;
  int x = threadIdx.x, y0 = threadIdx.y;
  for (int j = y0; j < 32; j += 8) tile[j][x] = W[(size_t)(k0 + j) * 1024 + n0 + x];
  __syncthreads();
  for (int j = y0; j < 32; j += 8) WT[(size_t)(n0 + j) * 1024 + k0 + x] = bf_from_f(tile[x][j]);
}

// u[t] = Wq[t,:].bk ; w2[i] = Wk[i,:].bq ; c0 = bq.bk ; also zero Sq/Sk.
// One wave per row, shuffle reduce.
__global__ __launch_bounds__(256) void k_uvc(const float* __restrict__ Wq,
    const float* __restrict__ Wk, const float* __restrict__ bq, const float* __restrict__ bk,
    float* __restrict__ u, float* __restrict__ w2, float* __restrict__ c0,
    float* __restrict__ Sq, float* __restrict__ Sk){
  int gw = blockIdx.x * 4 + (threadIdx.x >> 6);
  int lane = threadIdx.x & 63;
  if (gw < 2048){
    const float* row = (gw < 1024) ? (Wq + (size_t)gw * 1024) : (Wk + (size_t)(gw - 1024) * 1024);
    const float* vec = (gw < 1024) ? bk : bq;
    float s = 0;
    for (int m = lane; m < 1024; m += 64) s += row[m] * vec[m];
    for (int o = 32; o; o >>= 1) s += __shfl_down(s, o);
    if (lane == 0){ if (gw < 1024) u[gw] = s; else w2[gw - 1024] = s; }
  } else if (gw == 2048){
    float s = 0;
    for (int m = lane; m < 1024; m += 64) s += bq[m] * bk[m];
    for (int o = 32; o; o >>= 1) s += __shfl_down(s, o);
    if (lane == 0) c0[0] = s;
  } else if (gw == 2049){
    if (lane < 8){ Sq[lane] = 0.f; Sk[lane] = 0.f; }
  }
}

// ---------------- hs prep: ONE float4-vectorized pass over hs ----------------
// 64x64 (t,e) tile per block. Phase 1: 4x float4 loads/thread (all in flight),
// limbs written straight from registers, Sq/Sk partials in registers with a
// wave shuffle-reduce (no barrier tree). Phase 2: one barrier, float4 hsT stores.
__global__ __launch_bounds__(256) void k_prep_hs(const float* __restrict__ hs,
    u16* __restrict__ hi, u16* __restrict__ lo, float* __restrict__ hsT,
    const float* __restrict__ uu, const float* __restrict__ w2,
    float* __restrict__ Sq, float* __restrict__ Sk){
  __shared__ float tile[64][66];   // pitch 66: <=4-way banks on transposed read
  int b = blockIdx.z;
  int t0 = blockIdx.x * 64, e0 = blockIdx.y * 64;
  int tid = threadIdx.x;
  int eq = tid & 15;               // e-quad (16 quads * 4 = 64 e)
  int tr = tid >> 4;               // base t-row (0..15), rows tr + 16r
  const float* ib = hs + (size_t)b * 4194304;
  float4 u4 = *(const float4*)(uu + e0 + eq * 4);
  float4 w4 = *(const float4*)(w2 + e0 + eq * 4);
  float a1 = 0.f, a2 = 0.f;
  #pragma unroll
  for (int r = 0; r < 4; ++r){
    int t = tr + r * 16;
    size_t off = (size_t)(t0 + t) * 1024 + e0 + eq * 4;
    float4 v = *(const float4*)(ib + off);
    a1 += v.x * u4.x + v.y * u4.y + v.z * u4.z + v.w * u4.w;
    a2 += v.x * w4.x + v.y * w4.y + v.z * w4.z + v.w * w4.w;
    u16x4 h, l;
    h.x = bf_from_f(v.x); l.x = bf_from_f(v.x - f_from_bf(h.x));
    h.y = bf_from_f(v.y); l.y = bf_from_f(v.y - f_from_bf(h.y));
    h.z = bf_from_f(v.z); l.z = bf_from_f(v.z - f_from_bf(h.z));
    h.w = bf_from_f(v.w); l.w = bf_from_f(v.w - f_from_bf(h.w));
    size_t goff = (size_t)b * 4194304 + off;
    *(u16x4*)(hi + goff) = h; *(u16x4*)(lo + goff) = l;
    float* tp = &tile[t][eq * 4];
    tp[0] = v.x; tp[1] = v.y; tp[2] = v.z; tp[3] = v.w;
  }
  for (int o = 32; o; o >>= 1){
    a1 += __shfl_down(a1, o);
    a2 += __shfl_down(a2, o);
  }
  if ((tid & 63) == 0){ atomicAdd(&Sq[b], a1); atomicAdd(&Sk[b], a2); }
  __syncthreads();
  // transposed write: each thread stores float4 along t for 4 e-rows
  float* ob = hsT + (size_t)b * 4194304;
  int tq = tid & 15;               // t-quad
  int er = tid >> 4;               // base e-row (0..15), rows er + 16r
  #pragma unroll
  for (int r = 0; r < 4; ++r){
    int e = er + r * 16;
    float4 o4;
    o4.x = tile[tq * 4 + 0][e];
    o4.y = tile[tq * 4 + 1][e];
    o4.z = tile[tq * 4 + 2][e];
    o4.w = tile[tq * 4 + 3][e];
    *(float4*)(ob + (size_t)(e0 + e) * 4096 + t0 + tq * 4) = o4;
  }
}

// ---------------- GEMM (128x128 tile, 16x16x32 bf16 MFMA) ----------------
// A: [M,K] row-major bf16 (limbs). B: [N,K] row-major (i.e. math-B transposed).
// MODE 0: fp32 [M,N]; 1: P_t layout fp32 (b=n>>12, addr b*4M + m*4096 + (n&4095));
// MODE 2: bf16 [M,N] + bias[n]; 3: fp32 [M,N] + bias[n];
// MODE 4: split-bf16 limbs (outB=hi, outB2=lo), no bias.

DEVINL void stage_tile(const u16* __restrict__ src, int ld, int row0, int kb,
                       u16* lds, int wave, int lane){
  int r = lane >> 2, c = lane & 3;
  #pragma unroll
  for (int is = wave; is < 8; is += 4){
    const u16* g = src + (size_t)(row0 + is * 16 + r) * ld + kb + c * 8;
    async16((const void*)g, (void*)(lds + is * 512));  // lds base wave-uniform, lane*16B linear
  }
}

template<int SPLIT, int MODE>
DEVINL void gemm_body(const u16* __restrict__ Ah, const u16* __restrict__ Al,
                      const u16* __restrict__ Bh, const u16* __restrict__ Bl,
                      float* __restrict__ outF, u16* __restrict__ outB, u16* __restrict__ outB2,
                      const float* __restrict__ bias, int M, int N, int K,
                      int m0, int n0, u16* sAh, u16* sBh, u16* sAl, u16* sBl)
{
  int tid = threadIdx.x, wave = tid >> 6, lane = tid & 63;
  int wm = wave >> 1, wn = wave & 1;
  float4_t zero = {0.0f, 0.0f, 0.0f, 0.0f};
  float4_t acc[4][4];
  #pragma unroll
  for (int i = 0; i < 4; i++)
    #pragma unroll
    for (int j = 0; j < 4; j++) acc[i][j] = zero;

  int ar = wm * 64 + (lane & 15);
  int bc = wn * 64 + (lane & 15);
  int kq = (lane >> 4) * 8;

  for (int kb = 0; kb < K; kb += 32){
    stage_tile(Ah, K, m0, kb, sAh, wave, lane);
    stage_tile(Bh, K, n0, kb, sBh, wave, lane);
    if (SPLIT){
      stage_tile(Al, K, m0, kb, sAl, wave, lane);
      stage_tile(Bl, K, n0, kb, sBl, wave, lane);
    }
    __syncthreads();
    short8_t af[4], bfr[4], afl[4], bfl[4];
    #pragma unroll
    for (int i = 0; i < 4; i++){
      af[i]  = *(const short8_t*)(sAh + (ar + i * 16) * 32 + kq);
      bfr[i] = *(const short8_t*)(sBh + (bc + i * 16) * 32 + kq);
      if (SPLIT){
        afl[i] = *(const short8_t*)(sAl + (ar + i * 16) * 32 + kq);
        bfl[i] = *(const short8_t*)(sBl + (bc + i * 16) * 32 + kq);
      }
    }
    #pragma unroll
    for (int mi = 0; mi < 4; mi++)
      #pragma unroll
      for (int ni = 0; ni < 4; ni++){
        acc[mi][ni] = __builtin_amdgcn_mfma_f32_16x16x32_bf16(af[mi], bfr[ni], acc[mi][ni], 0, 0, 0);
        if (SPLIT){
          acc[mi][ni] = __builtin_amdgcn_mfma_f32_16x16x32_bf16(af[mi], bfl[ni], acc[mi][ni], 0, 0, 0);
          acc[mi][ni] = __builtin_amdgcn_mfma_f32_16x16x32_bf16(afl[mi], bfr[ni], acc[mi][ni], 0, 0, 0);
        }
      }
    __syncthreads();
  }

  int col = lane & 15, rq = lane >> 4;
  #pragma unroll
  for (int mi = 0; mi < 4; mi++)
    #pragma unroll
    for (int ni = 0; ni < 4; ni++){
      int gm = m0 + wm * 64 + mi * 16 + rq * 4;
      int gn = n0 + wn * 64 + ni * 16 + col;
      float4_t v = acc[mi][ni];
      #pragma unroll
      for (int r = 0; r < 4; r++){
        int row = gm + r;
        if (MODE == 0){
          outF[(size_t)row * N + gn] = v[r];
        } else if (MODE == 1){
          int bb = gn >> 12, t = gn & 4095;
          outF[(size_t)bb * 4194304 + (size_t)row * 4096 + t] = v[r];
        } else if (MODE == 2){
          outB[(size_t)row * N + gn] = bf_from_f(v[r] + bias[gn]);
        } else if (MODE == 3){
          outF[(size_t)row * N + gn] = v[r] + bias[gn];
        } else {
          float val = v[r];
          u16 h = bf_from_f(val);
          outB[(size_t)row * N + gn] = h;
          outB2[(size_t)row * N + gn] = bf_from_f(val - f_from_bf(h));
        }
      }
    }
}

template<int SPLIT, int MODE>
__global__ __launch_bounds__(256) void k_gemm128(
    const u16* __restrict__ Ah, const u16* __restrict__ Al,
    const u16* __restrict__ Bh, const u16* __restrict__ Bl,
    float* __restrict__ outF, u16* __restrict__ outB, u16* __restrict__ outB2,
    const float* __restrict__ bias, int M, int N, int K)
{
  __shared__ u16 sAh[128 * 32];
  __shared__ u16 sBh[128 * 32];
  __shared__ u16 sAl[SPLIT ? 128 * 32 : 8];
  __shared__ u16 sBl[SPLIT ? 128 * 32 : 8];
  gemm_body<SPLIT, MODE>(Ah, Al, Bh, Bl, outF, outB, outB2, bias, M, N, K,
                         blockIdx.y * 128, blockIdx.x * 128, sAh, sBh, sAl, sBl);
}

// P GEMM (blocks 0..2047, split, MODE 1) + V GEMM (blocks 2048..4095, MODE 2) in one launch.
__global__ __launch_bounds__(256) void k_gemm_pv(
    const u16* __restrict__ At_hi, const u16* __restrict__ At_lo,
    const u16* __restrict__ hs_hi, const u16* __restrict__ hs_lo,
    float* __restrict__ Pt, const u16* __restrict__ WvT, u16* __restrict__ Vb,
    const float* __restrict__ bv)
{
  __shared__ u16 smem[4 * 128 * 32];
  int bx = blockIdx.x;
  if (bx < 2048){
    gemm_body<1, 1>(At_hi, At_lo, hs_hi, hs_lo, Pt, nullptr, nullptr, nullptr,
                    1024, 32768, 1024, (bx >> 8) * 128, (bx & 255) * 128,
                    smem, smem + 4096, smem + 8192, smem + 12288);
  } else {
    int id = bx - 2048;
    gemm_body<0, 2>(hs_hi, nullptr, WvT, nullptr, nullptr, Vb, nullptr, bv,
                    32768, 1024, 1024, (id >> 3) * 128, (id & 7) * 128,
                    smem, smem + 4096, smem + 8192, smem + 12288);
  }
}

// ---------------- FFT forward (fused radix-4 DIF, SoA + pad, scrambled-domain unpack) ----

#define FPAD(i) ((i) + ((i) >> 3))

__global__ __launch_bounds__(256) void k_fft_fwd(const float* __restrict__ Pt,
                                                 const float* __restrict__ hsT,
                                                 float* __restrict__ S){
  __shared__ float zr[4608];
  __shared__ float zi[4608];
  int tid = threadIdx.x;
  int b = blockIdx.x >> 7;
  int ch0 = (blockIdx.x & 127) * 8;
  float Gre[8], Gim[8];
  #pragma unroll
  for (int j = 0; j < 8; ++j){ Gre[j] = 0.f; Gim[j] = 0.f; }
  float g0 = 0.f, g1 = 0.f;

  for (int c = 0; c < 8; ++c){
    __syncthreads();  // previous channel's unpack reads complete before overwrite
    size_t base = ((size_t)b * 1024 + ch0 + c) * 4096;
    for (int i = tid; i < 4096; i += 256){
      zr[FPAD(i)] = Pt[base + i];
      zi[FPAD(i)] = hsT[base + i];
    }
    // 6 fused radix-4 passes == 12 radix-2 DIF stages (identical math, bit-reversed out)
    for (int h = 1024; h >= 1; h >>= 2){
      __syncthreads();
      float wsc = -3.14159265358979323846f / (float)(2 * h);
      for (int g = tid; g < 1024; g += 256){
        int lo = g & (h - 1);
        int i0 = ((g - lo) << 2) + lo;
        int j0 = FPAD(i0), j1 = FPAD(i0 + h), j2 = FPAD(i0 + 2 * h), j3 = FPAD(i0 + 3 * h);
        float x0 = zr[j0], y0 = zi[j0];
        float x1 = zr[j1], y1 = zi[j1];
        float x2 = zr[j2], y2 = zi[j2];
        float x3 = zr[j3], y3 = zi[j3];
        float s, co;
        __sincosf(wsc * (float)lo, &s, &co);
        float b0x = x0 + x2, b0y = y0 + y2;
        float t2x = x0 - x2, t2y = y0 - y2;
        float b2x = t2x * co - t2y * s, b2y = t2x * s + t2y * co;
        float b1x = x1 + x3, b1y = y1 + y3;
        float t3x = x1 - x3, t3y = y1 - y3;
        float b3x = t3x * s + t3y * co, b3y = t3y * s - t3x * co;
        float vc = co * co - s * s, vs = 2.0f * co * s;
        float d1x = b0x - b1x, d1y = b0y - b1y;
        float d3x = b2x - b3x, d3y = b2y - b3y;
        zr[j0] = b0x + b1x;            zi[j0] = b0y + b1y;
        zr[j1] = d1x * vc - d1y * vs;  zi[j1] = d1x * vs + d1y * vc;
        zr[j2] = b2x + b3x;            zi[j2] = b2y + b3y;
        zr[j3] = d3x * vc - d3y * vs;  zi[j3] = d3x * vs + d3y * vc;
      }
    }
    __syncthreads();
    // scrambled-domain Hermitian-pair unpack, G accumulated in registers.
    #pragma unroll
    for (int j = 0; j < 8; ++j){
      int idx = tid + (j << 8);
      if (idx < 2047){
        int m = idx + 1;
        int e = 31 - __clz(m);
        int p = m + (1 << e);
        int q = (3 << (e + 1)) - 1 - p;
        int ip = FPAD(p), iq = FPAD(q);
        float xa = zr[ip], ya = zi[ip];
        float xb = zr[iq], yb = zi[iq];
        Gre[j] += 0.5f * (xa * yb + ya * xb);
        Gim[j] += 0.25f * ((xa * xa + ya * ya) - (xb * xb + yb * yb));
      }
    }
    if (tid == 0){
      g0 += zr[0] * zi[0];
      g1 += zr[FPAD(1)] * zi[FPAD(1)];
    }
  }

  float* Sb = S + (size_t)b * 2049 * 2;
  #pragma unroll
  for (int j = 0; j < 8; ++j){
    int idx = tid + (j << 8);
    if (idx < 2047){
      atomicAdd(&Sb[(2 + idx) * 2], Gre[j]);
      atomicAdd(&Sb[(2 + idx) * 2 + 1], Gim[j]);
    }
  }
  if (tid == 0){ atomicAdd(&Sb[0], g0); atomicAdd(&Sb[2], g1); }
}

// inverse + top-k fused: mean_ac lives only in LDS.
__global__ __launch_bounds__(256) void k_fft_inv_topk(const float* __restrict__ S,
    const float* __restrict__ Sq, const float* __restrict__ Sk,
    const float* __restrict__ c0, float* __restrict__ tv, int* __restrict__ ti){
  __shared__ cplx z[4096];
  __shared__ float vals[4096];
  __shared__ float rv[256];
  __shared__ int ri[256];
  int b = blockIdx.x, tid = threadIdx.x;
  const float* Sb = S + (size_t)b * 2049 * 2;
  #pragma unroll
  for (int j = 0; j < 8; ++j){
    int idx = tid + (j << 8);
    if (idx < 2047){
      int m = idx + 1;
      int e = 31 - __clz(m);
      int p = m + (1 << e);
      int q = (3 << (e + 1)) - 1 - p;
      float re = Sb[(2 + idx) * 2], im = Sb[(2 + idx) * 2 + 1];
      z[p].x = re; z[p].y = -im;
      z[q].x = re; z[q].y = im;
    }
  }
  if (tid == 0){
    z[0].x = Sb[0]; z[0].y = -Sb[1];
    z[1].x = Sb[2]; z[1].y = -Sb[3];
  }
  // DIT radix-2: bit-reversed input -> natural output
  for (int d = 1; d <= 2048; d <<= 1){
    __syncthreads();
    for (int j = tid; j < 2048; j += 256){
      int lo = j & (d - 1);
      int i = ((j & ~(d - 1)) << 1) | lo;
      float ang = -3.14159265358979323846f * (float)lo / (float)d;
      float s, co;
      __sincosf(ang, &s, &co);
      cplx av = z[i], bv = z[i + d];
      float tx = bv.x * co - bv.y * s;
      float ty = bv.x * s + bv.y * co;
      z[i].x = av.x + tx;     z[i].y = av.y + ty;
      z[i + d].x = av.x - tx; z[i + d].y = av.y - ty;
    }
  }
  __syncthreads();
  float constv = (Sq[b] + Sk[b] + 4096.0f * c0[0]) * (1.0f / 1024.0f);
  for (int t = tid; t < 4096; t += 256)
    vals[t] = z[t].x * (1.0f / 4194304.0f) + constv;
  __syncthreads();
  // top-24
  for (int it = 0; it < 24; ++it){
    float best = -3.0e38f; int bi = 0x7fffffff;
    for (int i = tid; i < 4096; i += 256){
      float v = vals[i];
      if (v > best){ best = v; bi = i; }
    }
    rv[tid] = best; ri[tid] = bi;
    __syncthreads();
    for (int s = 128; s > 0; s >>= 1){
      if (tid < s){
        if (rv[tid + s] > rv[tid] || (rv[tid + s] == rv[tid] && ri[tid + s] < ri[tid])){
          rv[tid] = rv[tid + s]; ri[tid] = ri[tid + s];
        }
      }
      __syncthreads();
    }
    if (tid == 0){
      tv[b * 24 + it] = rv[0]; ti[b * 24 + it] = ri[0];
      vals[ri[0]] = -3.0e38f;
    }
    __syncthreads();
  }
}

// ---------------- aggregation: agg[b,t,e] = sum_k w[h%8,k] * V[b,(t+d)%T,e] ----------------
// flat grid, b = blockIdx.x & 7 (XCD affinity: each XCD touches only V[b] = 8 MB);
// 16 B loads; (w,d) pairs in registers; k-loop fully unrolled.

__global__ __launch_bounds__(256, 4) void k_aggregate(const u16* __restrict__ V,
    const float* __restrict__ tv, const int* __restrict__ ti, u16* __restrict__ agg){
  __shared__ float wv[8][24];
  __shared__ int dv[8][24];
  int tid = threadIdx.x;
  if (tid < 192){ int s = tid / 24, k = tid % 24; wv[s][k] = tv[tid]; dv[s][k] = ti[tid]; }
  __syncthreads();
  int flat = blockIdx.x;           // 2048 blocks
  int b = flat & 7;                // XCD affinity
  int t0 = (flat >> 3) * 16;
  int oct = tid & 127;             // which 8-element e-group
  int th = tid >> 7;               // t parity within the pair
  int e = oct * 8;
  int sb = (oct >> 3) & 7;         // h % 8 (h = e/64)
  const u16* Vbase = V + (size_t)b * 4194304 + e;
  u16* abase = agg + (size_t)b * 4194304 + e;

  float wk[24]; int dk[24];
  #pragma unroll
  for (int k = 0; k < 24; ++k){ wk[k] = wv[sb][k]; dk[k] = dv[sb][k]; }

  for (int tt = 0; tt < 8; ++tt){
    int t = t0 + tt * 2 + th;
    float a0 = 0, a1 = 0, a2 = 0, a3 = 0, a4 = 0, a5 = 0, a6 = 0, a7 = 0;
    #pragma unroll
    for (int k = 0; k < 24; ++k){
      int st = (t + dk[k]) & 4095;
      int4 vv = *(const int4*)(Vbase + (size_t)st * 1024);
      float w = wk[k];
      a0 += w * __uint_as_float(((unsigned)vv.x) << 16);
      a1 += w * __uint_as_float(((unsigned)vv.x) & 0xFFFF0000u);
      a2 += w * __uint_as_float(((unsigned)vv.y) << 16);
      a3 += w * __uint_as_float(((unsigned)vv.y) & 0xFFFF0000u);
      a4 += w * __uint_as_float(((unsigned)vv.z) << 16);
      a5 += w * __uint_as_float(((unsigned)vv.z) & 0xFFFF0000u);
      a6 += w * __uint_as_float(((unsigned)vv.w) << 16);
      a7 += w * __uint_as_float(((unsigned)vv.w) & 0xFFFF0000u);
    }
    int4 o;
    o.x = (int)((unsigned)bf_from_f(a0) | ((unsigned)bf_from_f(a1) << 16));
    o.y = (int)((unsigned)bf_from_f(a2) | ((unsigned)bf_from_f(a3) << 16));
    o.z = (int)((unsigned)bf_from_f(a4) | ((unsigned)bf_from_f(a5) << 16));
    o.w = (int)((unsigned)bf_from_f(a6) | ((unsigned)bf_from_f(a7) << 16));
    *(int4*)(abase + (size_t)t * 1024) = o;
  }
}

// ---------------- launch ----------------

extern "C" void kernel_launch(void* const* d_in, const int* in_sizes, int n_in,
                              void* d_out, int out_size, void* d_ws, size_t ws_size,
                              hipStream_t stream){
  const float* hs = (const float*)d_in[0];
  const float* Wq = (const float*)d_in[1];
  const float* bq = (const float*)d_in[2];
  const float* Wk = (const float*)d_in[3];
  const float* bk = (const float*)d_in[4];
  const float* Wv = (const float*)d_in[5];
  const float* bv = (const float*)d_in[6];
  const float* Wo = (const float*)d_in[7];
  const float* bo = (const float*)d_in[8];

  char* ws = (char*)d_ws;
  const size_t MB = 1024ull * 1024ull;
  u16* hs_hi = (u16*)(ws);                 // 64MB; reused as agg after P/V GEMMs
  u16* hs_lo = (u16*)(ws + 64 * MB);       // 64MB
  float* Pt  = (float*)(ws + 128 * MB);    // 128MB  [B,E,T]
  float* hsT = (float*)(ws + 256 * MB);    // 128MB  [B,E,T]
  u16* Vb    = (u16*)(ws + 384 * MB);      // 64MB bf16 [B,T,E]
  char* sm   = ws + 448 * MB;
  u16* Wq_hi = (u16*)(sm + 0 * MB);
  u16* Wq_lo = (u16*)(sm + 2 * MB);
  u16* Wk_hi = (u16*)(sm + 4 * MB);
  u16* Wk_lo = (u16*)(sm + 6 * MB);
  u16* WvT   = (u16*)(sm + 8 * MB);
  u16* WoT   = (u16*)(sm + 10 * MB);
  u16* At_hi = (u16*)(sm + 16 * MB);
  u16* At_lo = (u16*)(sm + 18 * MB);
  float* S   = (float*)(sm + 20 * MB);     // 8 x 2049 pair-slots x 2 floats
  float* uu  = (float*)(sm + 22 * MB);
  float* w2  = (float*)(sm + 22 * MB + 8192);
  float* c0  = (float*)(sm + 22 * MB + 16384);
  float* Sq  = (float*)(sm + 22 * MB + 16640);
  float* Sk  = (float*)(sm + 22 * MB + 16896);
  float* tv  = (float*)(sm + 22 * MB + 17152);
  int*   ti  = (int*)(sm + 22 * MB + 18176);
  u16* agg   = hs_hi;

  hipMemsetAsync(S, 0, 8 * 2049 * 2 * sizeof(float), stream);

  k_uvc<<<513, 256, 0, stream>>>(Wq, Wk, bq, bk, uu, w2, c0, Sq, Sk);
  k_split2<<<2048, 256, 0, stream>>>(Wq, Wk, Wq_hi, Wq_lo, Wk_hi, Wk_lo);
  k_transpose2_bf16<<<dim3(32, 32, 2), dim3(32, 8), 0, stream>>>(Wv, Wo, WvT, WoT);
  k_prep_hs<<<dim3(64, 16, 8), 256, 0, stream>>>(hs, hs_hi, hs_lo, hsT, uu, w2, Sq, Sk);

  // At[e,k] = sum_m Wk[e,m] * Wq[k,m], split-bf16, limbs written directly
  k_gemm128<1, 4><<<dim3(8, 8), 256, 0, stream>>>(Wk_hi, Wk_lo, Wq_hi, Wq_lo,
                                                  nullptr, At_hi, At_lo, nullptr, 1024, 1024, 1024);
  // P^T (split, MODE 1) + V (MODE 2) in one launch
  k_gemm_pv<<<4096, 256, 0, stream>>>(At_hi, At_lo, hs_hi, hs_lo, Pt, WvT, Vb, bv);

  k_fft_fwd<<<1024, 256, 0, stream>>>(Pt, hsT, S);
  k_fft_inv_topk<<<8, 256, 0, stream>>>(S, Sq, Sk, c0, tv, ti);
  k_aggregate<<<2048, 256, 0, stream>>>(Vb, tv, ti, agg);
  // out = agg @ Wo + bo (fp32 out)
  k_gemm128<0, 3><<<dim3(8, 256), 256, 0, stream>>>(agg, nullptr, WoT, nullptr,
                                                    (float*)d_out, nullptr, nullptr, bo, 32768, 1024, 1024);
}

// Round 6
// 1126.737 us; speedup vs baseline: 1.2875x; 1.2868x over previous
//
#include <hip/hip_runtime.h>

// AutoformerAttention on MI355X.
// Pipeline:
//   At = Wk @ Wq^T (split-bf16 MFMA, limbs written directly from acc)
//   P  = hs @ At   (split-bf16 MFMA, stored transposed [B,E,T])   } fused in one
//   V  = hs @ Wv + bv (bf16 MFMA)                                 } launch (k_gemm_pv)
//   S[b,pair] = sum_e Pf * conj(HSf) via packed complex FFT (z = P + i*hs) per (b,e),
//     computed in the bit-reversed domain (pair q = 3*2^k-1-p), stride-1 unpack.
//   mean_ac = DIT-FFT(conj(S)) /(T*E) + const/E; top-24 fused in the same kernel.
//   agg[b,t,e] = sum_k w[h%8,k] * V[b,(t+d)%T,e]  -> out = agg @ Wo + bo
// hs is read ONCE (k_prep_hs). Sq/Sk use per-wave partials + late reduce —
// NO same-line atomics (32K atomicAdds to one cacheline was a 426 us serial stall).
// Workspace ~470 MB; agg aliases hs_hi (dead after the P/V GEMMs).

typedef unsigned short u16;
typedef __attribute__((ext_vector_type(8))) short short8_t;
typedef __attribute__((ext_vector_type(4))) float float4_t;

struct cplx { float x, y; };
struct __align__(8) u16x4 { u16 x, y, z, w; };

#define DEVINL static __device__ __forceinline__

DEVINL u16 bf_from_f(float x){
  unsigned u = __float_as_uint(x);
  u += 0x7fffu + ((u >> 16) & 1u);
  return (u16)(u >> 16);
}
DEVINL float f_from_bf(u16 h){ return __uint_as_float(((unsigned)h) << 16); }

typedef const void __attribute__((address_space(1)))* gas_ptr;
typedef void __attribute__((address_space(3)))* las_ptr;
DEVINL void async16(const void* g, void* l){
  __builtin_amdgcn_global_load_lds((gas_ptr)g, (las_ptr)l, 16, 0, 0);
}

// ---------------- weight prep ----------------

// split Wq and Wk into bf16 limbs in one launch (blocks 0..1023: Wq, 1024..2047: Wk)
__global__ void k_split2(const float* __restrict__ Wq, const float* __restrict__ Wk,
                         u16* __restrict__ Qh, u16* __restrict__ Ql,
                         u16* __restrict__ Kh, u16* __restrict__ Kl){
  int isK = blockIdx.x >> 10;
  int i = (blockIdx.x & 1023) * 256 + threadIdx.x;   // < 262144
  const float* src = isK ? Wk : Wq;
  u16* ph = isK ? Kh : Qh;
  u16* pl = isK ? Kl : Ql;
  float4 v = ((const float4*)src)[i];
  u16x4 h, l;
  h.x = bf_from_f(v.x); l.x = bf_from_f(v.x - f_from_bf(h.x));
  h.y = bf_from_f(v.y); l.y = bf_from_f(v.y - f_from_bf(h.y));
  h.z = bf_from_f(v.z); l.z = bf_from_f(v.z - f_from_bf(h.z));
  h.w = bf_from_f(v.w); l.w = bf_from_f(v.w - f_from_bf(h.w));
  ((u16x4*)ph)[i] = h; ((u16x4*)pl)[i] = l;
}

// WT[n][k] = bf16(W[k][n]) for Wv (z=0) and Wo (z=1), 1024x1024
__global__ void k_transpose2_bf16(const float* __restrict__ Wv, const float* __restrict__ Wo,
                                  u16* __restrict__ WvT, u16* __restrict__ WoT){
  __shared__ float tile[32][33];
  const float* W = blockIdx.z ? Wo : Wv;
  u16* WT = blockIdx.z ? WoT : WvT;
  int k0 = blockIdx.x * 32, n0 = blockIdx.y * 32;
  int x = threadIdx.x, y0 = threadIdx.y;
  for (int j = y0; j < 32; j += 8) tile[j][x] = W[(size_t)(k0 + j) * 1024 + n0 + x];
  __syncthreads();
  for (int j = y0; j < 32; j += 8) WT[(size_t)(n0 + j) * 1024 + k0 + x] = bf_from_f(tile[x][j]);
}

// u[t] = Wq[t,:].bk ; w2[i] = Wk[i,:].bq ; c0 = bq.bk. One wave per row, shuffle reduce.
__global__ __launch_bounds__(256) void k_uvc(const float* __restrict__ Wq,
    const float* __restrict__ Wk, const float* __restrict__ bq, const float* __restrict__ bk,
    float* __restrict__ u, float* __restrict__ w2, float* __restrict__ c0){
  int gw = blockIdx.x * 4 + (threadIdx.x >> 6);
  int lane = threadIdx.x & 63;
  if (gw < 2048){
    const float* row = (gw < 1024) ? (Wq + (size_t)gw * 1024) : (Wk + (size_t)(gw - 1024) * 1024);
    const float* vec = (gw < 1024) ? bk : bq;
    float s = 0;
    for (int m = lane; m < 1024; m += 64) s += row[m] * vec[m];
    for (int o = 32; o; o >>= 1) s += __shfl_down(s, o);
    if (lane == 0){ if (gw < 1024) u[gw] = s; else w2[gw - 1024] = s; }
  } else if (gw == 2048){
    float s = 0;
    for (int m = lane; m < 1024; m += 64) s += bq[m] * bk[m];
    for (int o = 32; o; o >>= 1) s += __shfl_down(s, o);
    if (lane == 0) c0[0] = s;
  }
}

// ---------------- hs prep: ONE float4-vectorized pass over hs ----------------
// 64x64 (t,e) tile per block. 4x float4 loads/thread, limbs straight from registers,
// Sq/Sk per-wave partials -> plain stores to partQ/partK (NO hot atomics).
__global__ __launch_bounds__(256) void k_prep_hs(const float* __restrict__ hs,
    u16* __restrict__ hi, u16* __restrict__ lo, float* __restrict__ hsT,
    const float* __restrict__ uu, const float* __restrict__ w2,
    float* __restrict__ partQ, float* __restrict__ partK){
  __shared__ float tile[64][66];   // pitch 66: <=4-way banks on transposed read
  int b = blockIdx.z;
  int t0 = blockIdx.x * 64, e0 = blockIdx.y * 64;
  int tid = threadIdx.x;
  int eq = tid & 15;               // e-quad (16 quads * 4 = 64 e)
  int tr = tid >> 4;               // base t-row (0..15), rows tr + 16r
  const float* ib = hs + (size_t)b * 4194304;
  float4 u4 = *(const float4*)(uu + e0 + eq * 4);
  float4 w4 = *(const float4*)(w2 + e0 + eq * 4);
  float a1 = 0.f, a2 = 0.f;
  #pragma unroll
  for (int r = 0; r < 4; ++r){
    int t = tr + r * 16;
    size_t off = (size_t)(t0 + t) * 1024 + e0 + eq * 4;
    float4 v = *(const float4*)(ib + off);
    a1 += v.x * u4.x + v.y * u4.y + v.z * u4.z + v.w * u4.w;
    a2 += v.x * w4.x + v.y * w4.y + v.z * w4.z + v.w * w4.w;
    u16x4 h, l;
    h.x = bf_from_f(v.x); l.x = bf_from_f(v.x - f_from_bf(h.x));
    h.y = bf_from_f(v.y); l.y = bf_from_f(v.y - f_from_bf(h.y));
    h.z = bf_from_f(v.z); l.z = bf_from_f(v.z - f_from_bf(h.z));
    h.w = bf_from_f(v.w); l.w = bf_from_f(v.w - f_from_bf(h.w));
    size_t goff = (size_t)b * 4194304 + off;
    *(u16x4*)(hi + goff) = h; *(u16x4*)(lo + goff) = l;
    float* tp = &tile[t][eq * 4];
    tp[0] = v.x; tp[1] = v.y; tp[2] = v.z; tp[3] = v.w;
  }
  for (int o = 32; o; o >>= 1){
    a1 += __shfl_down(a1, o);
    a2 += __shfl_down(a2, o);
  }
  if ((tid & 63) == 0){
    int idx = b * 4096 + (blockIdx.x * 16 + blockIdx.y) * 4 + (tid >> 6);
    partQ[idx] = a1; partK[idx] = a2;
  }
  __syncthreads();
  // transposed write: each thread stores float4 along t for 4 e-rows
  float* ob = hsT + (size_t)b * 4194304;
  int tq = tid & 15;               // t-quad
  int er = tid >> 4;               // base e-row (0..15), rows er + 16r
  #pragma unroll
  for (int r = 0; r < 4; ++r){
    int e = er + r * 16;
    float4 o4;
    o4.x = tile[tq * 4 + 0][e];
    o4.y = tile[tq * 4 + 1][e];
    o4.z = tile[tq * 4 + 2][e];
    o4.w = tile[tq * 4 + 3][e];
    *(float4*)(ob + (size_t)(e0 + e) * 4096 + t0 + tq * 4) = o4;
  }
}

// ---------------- GEMM (128x128 tile, 16x16x32 bf16 MFMA) ----------------
// A: [M,K] row-major bf16 (limbs). B: [N,K] row-major (i.e. math-B transposed).
// MODE 0: fp32 [M,N]; 1: P_t layout fp32 (b=n>>12, addr b*4M + m*4096 + (n&4095));
// MODE 2: bf16 [M,N] + bias[n]; 3: fp32 [M,N] + bias[n];
// MODE 4: split-bf16 limbs (outB=hi, outB2=lo), no bias.

DEVINL void stage_tile(const u16* __restrict__ src, int ld, int row0, int kb,
                       u16* lds, int wave, int lane){
  int r = lane >> 2, c = lane & 3;
  #pragma unroll
  for (int is = wave; is < 8; is += 4){
    const u16* g = src + (size_t)(row0 + is * 16 + r) * ld + kb + c * 8;
    async16((const void*)g, (void*)(lds + is * 512));  // lds base wave-uniform, lane*16B linear
  }
}

template<int SPLIT, int MODE>
DEVINL void gemm_body(const u16* __restrict__ Ah, const u16* __restrict__ Al,
                      const u16* __restrict__ Bh, const u16* __restrict__ Bl,
                      float* __restrict__ outF, u16* __restrict__ outB, u16* __restrict__ outB2,
                      const float* __restrict__ bias, int M, int N, int K,
                      int m0, int n0, u16* sAh, u16* sBh, u16* sAl, u16* sBl)
{
  int tid = threadIdx.x, wave = tid >> 6, lane = tid & 63;
  int wm = wave >> 1, wn = wave & 1;
  float4_t zero = {0.0f, 0.0f, 0.0f, 0.0f};
  float4_t acc[4][4];
  #pragma unroll
  for (int i = 0; i < 4; i++)
    #pragma unroll
    for (int j = 0; j < 4; j++) acc[i][j] = zero;

  int ar = wm * 64 + (lane & 15);
  int bc = wn * 64 + (lane & 15);
  int kq = (lane >> 4) * 8;

  for (int kb = 0; kb < K; kb += 32){
    stage_tile(Ah, K, m0, kb, sAh, wave, lane);
    stage_tile(Bh, K, n0, kb, sBh, wave, lane);
    if (SPLIT){
      stage_tile(Al, K, m0, kb, sAl, wave, lane);
      stage_tile(Bl, K, n0, kb, sBl, wave, lane);
    }
    __syncthreads();
    short8_t af[4], bfr[4], afl[4], bfl[4];
    #pragma unroll
    for (int i = 0; i < 4; i++){
      af[i]  = *(const short8_t*)(sAh + (ar + i * 16) * 32 + kq);
      bfr[i] = *(const short8_t*)(sBh + (bc + i * 16) * 32 + kq);
      if (SPLIT){
        afl[i] = *(const short8_t*)(sAl + (ar + i * 16) * 32 + kq);
        bfl[i] = *(const short8_t*)(sBl + (bc + i * 16) * 32 + kq);
      }
    }
    #pragma unroll
    for (int mi = 0; mi < 4; mi++)
      #pragma unroll
      for (int ni = 0; ni < 4; ni++){
        acc[mi][ni] = __builtin_amdgcn_mfma_f32_16x16x32_bf16(af[mi], bfr[ni], acc[mi][ni], 0, 0, 0);
        if (SPLIT){
          acc[mi][ni] = __builtin_amdgcn_mfma_f32_16x16x32_bf16(af[mi], bfl[ni], acc[mi][ni], 0, 0, 0);
          acc[mi][ni] = __builtin_amdgcn_mfma_f32_16x16x32_bf16(afl[mi], bfr[ni], acc[mi][ni], 0, 0, 0);
        }
      }
    __syncthreads();
  }

  int col = lane & 15, rq = lane >> 4;
  #pragma unroll
  for (int mi = 0; mi < 4; mi++)
    #pragma unroll
    for (int ni = 0; ni < 4; ni++){
      int gm = m0 + wm * 64 + mi * 16 + rq * 4;
      int gn = n0 + wn * 64 + ni * 16 + col;
      float4_t v = acc[mi][ni];
      #pragma unroll
      for (int r = 0; r < 4; r++){
        int row = gm + r;
        if (MODE == 0){
          outF[(size_t)row * N + gn] = v[r];
        } else if (MODE == 1){
          int bb = gn >> 12, t = gn & 4095;
          outF[(size_t)bb * 4194304 + (size_t)row * 4096 + t] = v[r];
        } else if (MODE == 2){
          outB[(size_t)row * N + gn] = bf_from_f(v[r] + bias[gn]);
        } else if (MODE == 3){
          outF[(size_t)row * N + gn] = v[r] + bias[gn];
        } else {
          float val = v[r];
          u16 h = bf_from_f(val);
          outB[(size_t)row * N + gn] = h;
          outB2[(size_t)row * N + gn] = bf_from_f(val - f_from_bf(h));
        }
      }
    }
}

template<int SPLIT, int MODE>
__global__ __launch_bounds__(256) void k_gemm128(
    const u16* __restrict__ Ah, const u16* __restrict__ Al,
    const u16* __restrict__ Bh, const u16* __restrict__ Bl,
    float* __restrict__ outF, u16* __restrict__ outB, u16* __restrict__ outB2,
    const float* __restrict__ bias, int M, int N, int K)
{
  __shared__ u16 sAh[128 * 32];
  __shared__ u16 sBh[128 * 32];
  __shared__ u16 sAl[SPLIT ? 128 * 32 : 8];
  __shared__ u16 sBl[SPLIT ? 128 * 32 : 8];
  gemm_body<SPLIT, MODE>(Ah, Al, Bh, Bl, outF, outB, outB2, bias, M, N, K,
                         blockIdx.y * 128, blockIdx.x * 128, sAh, sBh, sAl, sBl);
}

// P GEMM (blocks 0..2047, split, MODE 1) + V GEMM (blocks 2048..4095, MODE 2) in one launch.
__global__ __launch_bounds__(256) void k_gemm_pv(
    const u16* __restrict__ At_hi, const u16* __restrict__ At_lo,
    const u16* __restrict__ hs_hi, const u16* __restrict__ hs_lo,
    float* __restrict__ Pt, const u16* __restrict__ WvT, u16* __restrict__ Vb,
    const float* __restrict__ bv)
{
  __shared__ u16 smem[4 * 128 * 32];
  int bx = blockIdx.x;
  if (bx < 2048){
    gemm_body<1, 1>(At_hi, At_lo, hs_hi, hs_lo, Pt, nullptr, nullptr, nullptr,
                    1024, 32768, 1024, (bx >> 8) * 128, (bx & 255) * 128,
                    smem, smem + 4096, smem + 8192, smem + 12288);
  } else {
    int id = bx - 2048;
    gemm_body<0, 2>(hs_hi, nullptr, WvT, nullptr, nullptr, Vb, nullptr, bv,
                    32768, 1024, 1024, (id >> 3) * 128, (id & 7) * 128,
                    smem, smem + 4096, smem + 8192, smem + 12288);
  }
}

// ---------------- FFT forward (fused radix-4 DIF, SoA + pad, scrambled-domain unpack) ----

#define FPAD(i) ((i) + ((i) >> 3))

__global__ __launch_bounds__(256) void k_fft_fwd(const float* __restrict__ Pt,
                                                 const float* __restrict__ hsT,
                                                 float* __restrict__ S){
  __shared__ float zr[4608];
  __shared__ float zi[4608];
  int tid = threadIdx.x;
  int b = blockIdx.x >> 7;
  int ch0 = (blockIdx.x & 127) * 8;
  float Gre[8], Gim[8];
  #pragma unroll
  for (int j = 0; j < 8; ++j){ Gre[j] = 0.f; Gim[j] = 0.f; }
  float g0 = 0.f, g1 = 0.f;

  for (int c = 0; c < 8; ++c){
    __syncthreads();  // previous channel's unpack reads complete before overwrite
    size_t base = ((size_t)b * 1024 + ch0 + c) * 4096;
    for (int i = tid; i < 4096; i += 256){
      zr[FPAD(i)] = Pt[base + i];
      zi[FPAD(i)] = hsT[base + i];
    }
    // 6 fused radix-4 passes == 12 radix-2 DIF stages (identical math, bit-reversed out)
    for (int h = 1024; h >= 1; h >>= 2){
      __syncthreads();
      float wsc = -3.14159265358979323846f / (float)(2 * h);
      for (int g = tid; g < 1024; g += 256){
        int lo = g & (h - 1);
        int i0 = ((g - lo) << 2) + lo;
        int j0 = FPAD(i0), j1 = FPAD(i0 + h), j2 = FPAD(i0 + 2 * h), j3 = FPAD(i0 + 3 * h);
        float x0 = zr[j0], y0 = zi[j0];
        float x1 = zr[j1], y1 = zi[j1];
        float x2 = zr[j2], y2 = zi[j2];
        float x3 = zr[j3], y3 = zi[j3];
        float s, co;
        __sincosf(wsc * (float)lo, &s, &co);
        float b0x = x0 + x2, b0y = y0 + y2;
        float t2x = x0 - x2, t2y = y0 - y2;
        float b2x = t2x * co - t2y * s, b2y = t2x * s + t2y * co;
        float b1x = x1 + x3, b1y = y1 + y3;
        float t3x = x1 - x3, t3y = y1 - y3;
        float b3x = t3x * s + t3y * co, b3y = t3y * s - t3x * co;
        float vc = co * co - s * s, vs = 2.0f * co * s;
        float d1x = b0x - b1x, d1y = b0y - b1y;
        float d3x = b2x - b3x, d3y = b2y - b3y;
        zr[j0] = b0x + b1x;            zi[j0] = b0y + b1y;
        zr[j1] = d1x * vc - d1y * vs;  zi[j1] = d1x * vs + d1y * vc;
        zr[j2] = b2x + b3x;            zi[j2] = b2y + b3y;
        zr[j3] = d3x * vc - d3y * vs;  zi[j3] = d3x * vs + d3y * vc;
      }
    }
    __syncthreads();
    // scrambled-domain Hermitian-pair unpack, G accumulated in registers.
    #pragma unroll
    for (int j = 0; j < 8; ++j){
      int idx = tid + (j << 8);
      if (idx < 2047){
        int m = idx + 1;
        int e = 31 - __clz(m);
        int p = m + (1 << e);
        int q = (3 << (e + 1)) - 1 - p;
        int ip = FPAD(p), iq = FPAD(q);
        float xa = zr[ip], ya = zi[ip];
        float xb = zr[iq], yb = zi[iq];
        Gre[j] += 0.5f * (xa * yb + ya * xb);
        Gim[j] += 0.25f * ((xa * xa + ya * ya) - (xb * xb + yb * yb));
      }
    }
    if (tid == 0){
      g0 += zr[0] * zi[0];
      g1 += zr[FPAD(1)] * zi[FPAD(1)];
    }
  }

  float* Sb = S + (size_t)b * 2049 * 2;
  #pragma unroll
  for (int j = 0; j < 8; ++j){
    int idx = tid + (j << 8);
    if (idx < 2047){
      atomicAdd(&Sb[(2 + idx) * 2], Gre[j]);
      atomicAdd(&Sb[(2 + idx) * 2 + 1], Gim[j]);
    }
  }
  if (tid == 0){ atomicAdd(&Sb[0], g0); atomicAdd(&Sb[2], g1); }
}

// inverse + top-k fused; also reduces the Sq/Sk per-wave partials (4096 each per b).
__global__ __launch_bounds__(256) void k_fft_inv_topk(const float* __restrict__ S,
    const float* __restrict__ partQ, const float* __restrict__ partK,
    const float* __restrict__ c0, float* __restrict__ tv, int* __restrict__ ti){
  __shared__ cplx z[4096];
  __shared__ float vals[4096];
  __shared__ float rv[256];
  __shared__ int ri[256];
  __shared__ float sred[8];
  int b = blockIdx.x, tid = threadIdx.x;
  // reduce Sq/Sk partials
  {
    const float* pQ = partQ + (size_t)b * 4096;
    const float* pK = partK + (size_t)b * 4096;
    float aq = 0.f, ak = 0.f;
    for (int i = tid; i < 4096; i += 256){ aq += pQ[i]; ak += pK[i]; }
    for (int o = 32; o; o >>= 1){ aq += __shfl_down(aq, o); ak += __shfl_down(ak, o); }
    if ((tid & 63) == 0){ sred[tid >> 6] = aq; sred[4 + (tid >> 6)] = ak; }
  }
  const float* Sb = S + (size_t)b * 2049 * 2;
  #pragma unroll
  for (int j = 0; j < 8; ++j){
    int idx = tid + (j << 8);
    if (idx < 2047){
      int m = idx + 1;
      int e = 31 - __clz(m);
      int p = m + (1 << e);
      int q = (3 << (e + 1)) - 1 - p;
      float re = Sb[(2 + idx) * 2], im = Sb[(2 + idx) * 2 + 1];
      z[p].x = re; z[p].y = -im;
      z[q].x = re; z[q].y = im;
    }
  }
  if (tid == 0){
    z[0].x = Sb[0]; z[0].y = -Sb[1];
    z[1].x = Sb[2]; z[1].y = -Sb[3];
  }
  // DIT radix-2: bit-reversed input -> natural output
  for (int d = 1; d <= 2048; d <<= 1){
    __syncthreads();
    for (int j = tid; j < 2048; j += 256){
      int lo = j & (d - 1);
      int i = ((j & ~(d - 1)) << 1) | lo;
      float ang = -3.14159265358979323846f * (float)lo / (float)d;
      float s, co;
      __sincosf(ang, &s, &co);
      cplx av = z[i], bv = z[i + d];
      float tx = bv.x * co - bv.y * s;
      float ty = bv.x * s + bv.y * co;
      z[i].x = av.x + tx;     z[i].y = av.y + ty;
      z[i + d].x = av.x - tx; z[i + d].y = av.y - ty;
    }
  }
  __syncthreads();
  float Sqb = sred[0] + sred[1] + sred[2] + sred[3];
  float Skb = sred[4] + sred[5] + sred[6] + sred[7];
  float constv = (Sqb + Skb + 4096.0f * c0[0]) * (1.0f / 1024.0f);
  for (int t = tid; t < 4096; t += 256)
    vals[t] = z[t].x * (1.0f / 4194304.0f) + constv;
  __syncthreads();
  // top-24
  for (int it = 0; it < 24; ++it){
    float best = -3.0e38f; int bi = 0x7fffffff;
    for (int i = tid; i < 4096; i += 256){
      float v = vals[i];
      if (v > best){ best = v; bi = i; }
    }
    rv[tid] = best; ri[tid] = bi;
    __syncthreads();
    for (int s = 128; s > 0; s >>= 1){
      if (tid < s){
        if (rv[tid + s] > rv[tid] || (rv[tid + s] == rv[tid] && ri[tid + s] < ri[tid])){
          rv[tid] = rv[tid + s]; ri[tid] = ri[tid + s];
        }
      }
      __syncthreads();
    }
    if (tid == 0){
      tv[b * 24 + it] = rv[0]; ti[b * 24 + it] = ri[0];
      vals[ri[0]] = -3.0e38f;
    }
    __syncthreads();
  }
}

// ---------------- aggregation: agg[b,t,e] = sum_k w[h%8,k] * V[b,(t+d)%T,e] ----------------
// flat grid, b = blockIdx.x & 7 (XCD affinity: each XCD touches only V[b] = 8 MB);
// 16 B loads; (w,d) pairs in registers; k-loop fully unrolled.

__global__ __launch_bounds__(256, 4) void k_aggregate(const u16* __restrict__ V,
    const float* __restrict__ tv, const int* __restrict__ ti, u16* __restrict__ agg){
  __shared__ float wv[8][24];
  __shared__ int dv[8][24];
  int tid = threadIdx.x;
  if (tid < 192){ int s = tid / 24, k = tid % 24; wv[s][k] = tv[tid]; dv[s][k] = ti[tid]; }
  __syncthreads();
  int flat = blockIdx.x;           // 2048 blocks
  int b = flat & 7;                // XCD affinity
  int t0 = (flat >> 3) * 16;
  int oct = tid & 127;             // which 8-element e-group
  int th = tid >> 7;               // t parity within the pair
  int e = oct * 8;
  int sb = (oct >> 3) & 7;         // h % 8 (h = e/64)
  const u16* Vbase = V + (size_t)b * 4194304 + e;
  u16* abase = agg + (size_t)b * 4194304 + e;

  float wk[24]; int dk[24];
  #pragma unroll
  for (int k = 0; k < 24; ++k){ wk[k] = wv[sb][k]; dk[k] = dv[sb][k]; }

  for (int tt = 0; tt < 8; ++tt){
    int t = t0 + tt * 2 + th;
    float a0 = 0, a1 = 0, a2 = 0, a3 = 0, a4 = 0, a5 = 0, a6 = 0, a7 = 0;
    #pragma unroll
    for (int k = 0; k < 24; ++k){
      int st = (t + dk[k]) & 4095;
      int4 vv = *(const int4*)(Vbase + (size_t)st * 1024);
      float w = wk[k];
      a0 += w * __uint_as_float(((unsigned)vv.x) << 16);
      a1 += w * __uint_as_float(((unsigned)vv.x) & 0xFFFF0000u);
      a2 += w * __uint_as_float(((unsigned)vv.y) << 16);
      a3 += w * __uint_as_float(((unsigned)vv.y) & 0xFFFF0000u);
      a4 += w * __uint_as_float(((unsigned)vv.z) << 16);
      a5 += w * __uint_as_float(((unsigned)vv.z) & 0xFFFF0000u);
      a6 += w * __uint_as_float(((unsigned)vv.w) << 16);
      a7 += w * __uint_as_float(((unsigned)vv.w) & 0xFFFF0000u);
    }
    int4 o;
    o.x = (int)((unsigned)bf_from_f(a0) | ((unsigned)bf_from_f(a1) << 16));
    o.y = (int)((unsigned)bf_from_f(a2) | ((unsigned)bf_from_f(a3) << 16));
    o.z = (int)((unsigned)bf_from_f(a4) | ((unsigned)bf_from_f(a5) << 16));
    o.w = (int)((unsigned)bf_from_f(a6) | ((unsigned)bf_from_f(a7) << 16));
    *(int4*)(abase + (size_t)t * 1024) = o;
  }
}

// ---------------- launch ----------------

extern "C" void kernel_launch(void* const* d_in, const int* in_sizes, int n_in,
                              void* d_out, int out_size, void* d_ws, size_t ws_size,
                              hipStream_t stream){
  const float* hs = (const float*)d_in[0];
  const float* Wq = (const float*)d_in[1];
  const float* bq = (const float*)d_in[2];
  const float* Wk = (const float*)d_in[3];
  const float* bk = (const float*)d_in[4];
  const float* Wv = (const float*)d_in[5];
  const float* bv = (const float*)d_in[6];
  const float* Wo = (const float*)d_in[7];
  const float* bo = (const float*)d_in[8];

  char* ws = (char*)d_ws;
  const size_t MB = 1024ull * 1024ull;
  u16* hs_hi = (u16*)(ws);                 // 64MB; reused as agg after P/V GEMMs
  u16* hs_lo = (u16*)(ws + 64 * MB);       // 64MB
  float* Pt  = (float*)(ws + 128 * MB);    // 128MB  [B,E,T]
  float* hsT = (float*)(ws + 256 * MB);    // 128MB  [B,E,T]
  u16* Vb    = (u16*)(ws + 384 * MB);      // 64MB bf16 [B,T,E]
  char* sm   = ws + 448 * MB;
  u16* Wq_hi = (u16*)(sm + 0 * MB);
  u16* Wq_lo = (u16*)(sm + 2 * MB);
  u16* Wk_hi = (u16*)(sm + 4 * MB);
  u16* Wk_lo = (u16*)(sm + 6 * MB);
  u16* WvT   = (u16*)(sm + 8 * MB);
  u16* WoT   = (u16*)(sm + 10 * MB);
  float* partQ = (float*)(sm + 12 * MB);   // 8 x 4096 per-wave partials (128 KB)
  float* partK = (float*)(sm + 13 * MB);   // 8 x 4096 (128 KB)
  u16* At_hi = (u16*)(sm + 16 * MB);
  u16* At_lo = (u16*)(sm + 18 * MB);
  float* S   = (float*)(sm + 20 * MB);     // 8 x 2049 pair-slots x 2 floats
  float* uu  = (float*)(sm + 22 * MB);
  float* w2  = (float*)(sm + 22 * MB + 8192);
  float* c0  = (float*)(sm + 22 * MB + 16384);
  float* tv  = (float*)(sm + 22 * MB + 17152);
  int*   ti  = (int*)(sm + 22 * MB + 18176);
  u16* agg   = hs_hi;

  hipMemsetAsync(S, 0, 8 * 2049 * 2 * sizeof(float), stream);

  k_uvc<<<513, 256, 0, stream>>>(Wq, Wk, bq, bk, uu, w2, c0);
  k_split2<<<2048, 256, 0, stream>>>(Wq, Wk, Wq_hi, Wq_lo, Wk_hi, Wk_lo);
  k_transpose2_bf16<<<dim3(32, 32, 2), dim3(32, 8), 0, stream>>>(Wv, Wo, WvT, WoT);
  k_prep_hs<<<dim3(64, 16, 8), 256, 0, stream>>>(hs, hs_hi, hs_lo, hsT, uu, w2, partQ, partK);

  // At[e,k] = sum_m Wk[e,m] * Wq[k,m], split-bf16, limbs written directly
  k_gemm128<1, 4><<<dim3(8, 8), 256, 0, stream>>>(Wk_hi, Wk_lo, Wq_hi, Wq_lo,
                                                  nullptr, At_hi, At_lo, nullptr, 1024, 1024, 1024);
  // P^T (split, MODE 1) + V (MODE 2) in one launch
  k_gemm_pv<<<4096, 256, 0, stream>>>(At_hi, At_lo, hs_hi, hs_lo, Pt, WvT, Vb, bv);

  k_fft_fwd<<<1024, 256, 0, stream>>>(Pt, hsT, S);
  k_fft_inv_topk<<<8, 256, 0, stream>>>(S, partQ, partK, c0, tv, ti);
  k_aggregate<<<2048, 256, 0, stream>>>(Vb, tv, ti, agg);
  // out = agg @ Wo + bo (fp32 out)
  k_gemm128<0, 3><<<dim3(8, 256), 256, 0, stream>>>(agg, nullptr, WoT, nullptr,
                                                    (float*)d_out, nullptr, nullptr, bo, 32768, 1024, 1024);
}

// Round 8
// 1095.225 us; speedup vs baseline: 1.3245x; 1.0288x over previous
//
#include <hip/hip_runtime.h>

// AutoformerAttention on MI355X.
// Pipeline:
//   At = Wk @ Wq^T (split-bf16 MFMA, limbs written directly from acc)
//   P  = hs @ At   (split-bf16 MFMA, stored transposed [B,E,T])   } fused in one
//   V  = hs @ Wv + bv (bf16 MFMA)                                 } launch (k_gemm_pv)
//   S[b,pair] = sum_e Pf * conj(HSf) via packed complex FFT (z = P + i*hs) per (b,e),
//     computed in the bit-reversed domain (pair q = 3*2^k-1-p), stride-1 unpack.
//   mean_ac = DIT-FFT(conj(S)) /(T*E) + const/E; top-24 fused in the same kernel.
//   agg[b,t,e] = sum_k w[h%8,k] * V[b,(t+d)%T,e]  -> out = agg @ Wo + bo
// hs is read ONCE (k_prep_hs). Sq/Sk use per-wave partials + late reduce (no hot atomics).
// k_gemm_pv uses an XCD-aware block remap (same-B-slice m-tiles consecutive on one XCD)
// and non-temporal stores for write-only streams (Pt/Vb/out/hsT) to keep L2/L3 for hs.
// Workspace ~470 MB; agg aliases hs_hi (dead after the P/V GEMMs).

typedef unsigned short u16;
typedef __attribute__((ext_vector_type(8))) short short8_t;
typedef __attribute__((ext_vector_type(4))) float float4_t;

struct cplx { float x, y; };
struct __align__(8) u16x4 { u16 x, y, z, w; };

#define DEVINL static __device__ __forceinline__

DEVINL u16 bf_from_f(float x){
  unsigned u = __float_as_uint(x);
  u += 0x7fffu + ((u >> 16) & 1u);
  return (u16)(u >> 16);
}
DEVINL float f_from_bf(u16 h){ return __uint_as_float(((unsigned)h) << 16); }

DEVINL void nt_store_f(float* p, float v){ __builtin_nontemporal_store(v, p); }
DEVINL void nt_store_u16(u16* p, u16 v){ __builtin_nontemporal_store(v, p); }
DEVINL void nt_store_f4(float* p, float4_t v){ __builtin_nontemporal_store(v, (float4_t*)p); }

typedef const void __attribute__((address_space(1)))* gas_ptr;
typedef void __attribute__((address_space(3)))* las_ptr;
DEVINL void async16(const void* g, void* l){
  __builtin_amdgcn_global_load_lds((gas_ptr)g, (las_ptr)l, 16, 0, 0);
}

// ---------------- weight prep ----------------

// split Wq and Wk into bf16 limbs in one launch (blocks 0..1023: Wq, 1024..2047: Wk)
__global__ void k_split2(const float* __restrict__ Wq, const float* __restrict__ Wk,
                         u16* __restrict__ Qh, u16* __restrict__ Ql,
                         u16* __restrict__ Kh, u16* __restrict__ Kl){
  int isK = blockIdx.x >> 10;
  int i = (blockIdx.x & 1023) * 256 + threadIdx.x;   // < 262144
  const float* src = isK ? Wk : Wq;
  u16* ph = isK ? Kh : Qh;
  u16* pl = isK ? Kl : Ql;
  float4 v = ((const float4*)src)[i];
  u16x4 h, l;
  h.x = bf_from_f(v.x); l.x = bf_from_f(v.x - f_from_bf(h.x));
  h.y = bf_from_f(v.y); l.y = bf_from_f(v.y - f_from_bf(h.y));
  h.z = bf_from_f(v.z); l.z = bf_from_f(v.z - f_from_bf(h.z));
  h.w = bf_from_f(v.w); l.w = bf_from_f(v.w - f_from_bf(h.w));
  ((u16x4*)ph)[i] = h; ((u16x4*)pl)[i] = l;
}

// WT[n][k] = bf16(W[k][n]) for Wv (z=0) and Wo (z=1), 1024x1024
__global__ void k_transpose2_bf16(const float* __restrict__ Wv, const float* __restrict__ Wo,
                                  u16* __restrict__ WvT, u16* __restrict__ WoT){
  __shared__ float tile[32][33];
  const float* W = blockIdx.z ? Wo : Wv;
  u16* WT = blockIdx.z ? WoT : WvT;
  int k0 = blockIdx.x * 32, n0 = blockIdx.y * 32;
  int x = threadIdx.x, y0 = threadIdx.y;
  for (int j = y0; j < 32; j += 8) tile[j][x] = W[(size_t)(k0 + j) * 1024 + n0 + x];
  __syncthreads();
  for (int j = y0; j < 32; j += 8) WT[(size_t)(n0 + j) * 1024 + k0 + x] = bf_from_f(tile[x][j]);
}

// u[t] = Wq[t,:].bk ; w2[i] = Wk[i,:].bq ; c0 = bq.bk. One wave per row, shuffle reduce.
__global__ __launch_bounds__(256) void k_uvc(const float* __restrict__ Wq,
    const float* __restrict__ Wk, const float* __restrict__ bq, const float* __restrict__ bk,
    float* __restrict__ u, float* __restrict__ w2, float* __restrict__ c0){
  int gw = blockIdx.x * 4 + (threadIdx.x >> 6);
  int lane = threadIdx.x & 63;
  if (gw < 2048){
    const float* row = (gw < 1024) ? (Wq + (size_t)gw * 1024) : (Wk + (size_t)(gw - 1024) * 1024);
    const float* vec = (gw < 1024) ? bk : bq;
    float s = 0;
    for (int m = lane; m < 1024; m += 64) s += row[m] * vec[m];
    for (int o = 32; o; o >>= 1) s += __shfl_down(s, o);
    if (lane == 0){ if (gw < 1024) u[gw] = s; else w2[gw - 1024] = s; }
  } else if (gw == 2048){
    float s = 0;
    for (int m = lane; m < 1024; m += 64) s += bq[m] * bk[m];
    for (int o = 32; o; o >>= 1) s += __shfl_down(s, o);
    if (lane == 0) c0[0] = s;
  }
}

// ---------------- hs prep: ONE float4-vectorized pass over hs ----------------
// 64x64 (t,e) tile per block. 4x float4 loads/thread, limbs straight from registers,
// Sq/Sk per-wave partials -> plain stores to partQ/partK (NO hot atomics).
__global__ __launch_bounds__(256) void k_prep_hs(const float* __restrict__ hs,
    u16* __restrict__ hi, u16* __restrict__ lo, float* __restrict__ hsT,
    const float* __restrict__ uu, const float* __restrict__ w2,
    float* __restrict__ partQ, float* __restrict__ partK){
  __shared__ float tile[64][66];   // pitch 66: <=4-way banks on transposed read
  int b = blockIdx.z;
  int t0 = blockIdx.x * 64, e0 = blockIdx.y * 64;
  int tid = threadIdx.x;
  int eq = tid & 15;               // e-quad (16 quads * 4 = 64 e)
  int tr = tid >> 4;               // base t-row (0..15), rows tr + 16r
  const float* ib = hs + (size_t)b * 4194304;
  float4 u4 = *(const float4*)(uu + e0 + eq * 4);
  float4 w4 = *(const float4*)(w2 + e0 + eq * 4);
  float a1 = 0.f, a2 = 0.f;
  #pragma unroll
  for (int r = 0; r < 4; ++r){
    int t = tr + r * 16;
    size_t off = (size_t)(t0 + t) * 1024 + e0 + eq * 4;
    float4 v = *(const float4*)(ib + off);
    a1 += v.x * u4.x + v.y * u4.y + v.z * u4.z + v.w * u4.w;
    a2 += v.x * w4.x + v.y * w4.y + v.z * w4.z + v.w * w4.w;
    u16x4 h, l;
    h.x = bf_from_f(v.x); l.x = bf_from_f(v.x - f_from_bf(h.x));
    h.y = bf_from_f(v.y); l.y = bf_from_f(v.y - f_from_bf(h.y));
    h.z = bf_from_f(v.z); l.z = bf_from_f(v.z - f_from_bf(h.z));
    h.w = bf_from_f(v.w); l.w = bf_from_f(v.w - f_from_bf(h.w));
    size_t goff = (size_t)b * 4194304 + off;
    *(u16x4*)(hi + goff) = h; *(u16x4*)(lo + goff) = l;
    float* tp = &tile[t][eq * 4];
    tp[0] = v.x; tp[1] = v.y; tp[2] = v.z; tp[3] = v.w;
  }
  for (int o = 32; o; o >>= 1){
    a1 += __shfl_down(a1, o);
    a2 += __shfl_down(a2, o);
  }
  if ((tid & 63) == 0){
    int idx = b * 4096 + (blockIdx.x * 16 + blockIdx.y) * 4 + (tid >> 6);
    partQ[idx] = a1; partK[idx] = a2;
  }
  __syncthreads();
  // transposed write (non-temporal: hsT is only read after gemm_pv has run)
  float* ob = hsT + (size_t)b * 4194304;
  int tq = tid & 15;               // t-quad
  int er = tid >> 4;               // base e-row (0..15), rows er + 16r
  #pragma unroll
  for (int r = 0; r < 4; ++r){
    int e = er + r * 16;
    float4_t o4;
    o4.x = tile[tq * 4 + 0][e];
    o4.y = tile[tq * 4 + 1][e];
    o4.z = tile[tq * 4 + 2][e];
    o4.w = tile[tq * 4 + 3][e];
    nt_store_f4(ob + (size_t)(e0 + e) * 4096 + t0 + tq * 4, o4);
  }
}

// ---------------- GEMM (128x128 tile, 16x16x32 bf16 MFMA) ----------------
// A: [M,K] row-major bf16 (limbs). B: [N,K] row-major (i.e. math-B transposed).
// MODE 0: fp32 [M,N]; 1: P_t layout fp32 (b=n>>12, addr b*4M + m*4096 + (n&4095)), NT;
// MODE 2: bf16 [M,N] + bias[n], NT; 3: fp32 [M,N] + bias[n], NT;
// MODE 4: split-bf16 limbs (outB=hi, outB2=lo), no bias.

DEVINL void stage_tile(const u16* __restrict__ src, int ld, int row0, int kb,
                       u16* lds, int wave, int lane){
  int r = lane >> 2, c = lane & 3;
  #pragma unroll
  for (int is = wave; is < 8; is += 4){
    const u16* g = src + (size_t)(row0 + is * 16 + r) * ld + kb + c * 8;
    async16((const void*)g, (void*)(lds + is * 512));  // lds base wave-uniform, lane*16B linear
  }
}

template<int SPLIT, int MODE>
DEVINL void gemm_body(const u16* __restrict__ Ah, const u16* __restrict__ Al,
                      const u16* __restrict__ Bh, const u16* __restrict__ Bl,
                      float* __restrict__ outF, u16* __restrict__ outB, u16* __restrict__ outB2,
                      const float* __restrict__ bias, int M, int N, int K,
                      int m0, int n0, u16* sAh, u16* sBh, u16* sAl, u16* sBl)
{
  int tid = threadIdx.x, wave = tid >> 6, lane = tid & 63;
  int wm = wave >> 1, wn = wave & 1;
  float4_t zero = {0.0f, 0.0f, 0.0f, 0.0f};
  float4_t acc[4][4];
  #pragma unroll
  for (int i = 0; i < 4; i++)
    #pragma unroll
    for (int j = 0; j < 4; j++) acc[i][j] = zero;

  int ar = wm * 64 + (lane & 15);
  int bc = wn * 64 + (lane & 15);
  int kq = (lane >> 4) * 8;

  for (int kb = 0; kb < K; kb += 32){
    stage_tile(Ah, K, m0, kb, sAh, wave, lane);
    stage_tile(Bh, K, n0, kb, sBh, wave, lane);
    if (SPLIT){
      stage_tile(Al, K, m0, kb, sAl, wave, lane);
      stage_tile(Bl, K, n0, kb, sBl, wave, lane);
    }
    __syncthreads();
    short8_t af[4], bfr[4], afl[4], bfl[4];
    #pragma unroll
    for (int i = 0; i < 4; i++){
      af[i]  = *(const short8_t*)(sAh + (ar + i * 16) * 32 + kq);
      bfr[i] = *(const short8_t*)(sBh + (bc + i * 16) * 32 + kq);
      if (SPLIT){
        afl[i] = *(const short8_t*)(sAl + (ar + i * 16) * 32 + kq);
        bfl[i] = *(const short8_t*)(sBl + (bc + i * 16) * 32 + kq);
      }
    }
    #pragma unroll
    for (int mi = 0; mi < 4; mi++)
      #pragma unroll
      for (int ni = 0; ni < 4; ni++){
        acc[mi][ni] = __builtin_amdgcn_mfma_f32_16x16x32_bf16(af[mi], bfr[ni], acc[mi][ni], 0, 0, 0);
        if (SPLIT){
          acc[mi][ni] = __builtin_amdgcn_mfma_f32_16x16x32_bf16(af[mi], bfl[ni], acc[mi][ni], 0, 0, 0);
          acc[mi][ni] = __builtin_amdgcn_mfma_f32_16x16x32_bf16(afl[mi], bfr[ni], acc[mi][ni], 0, 0, 0);
        }
      }
    __syncthreads();
  }

  int col = lane & 15, rq = lane >> 4;
  #pragma unroll
  for (int mi = 0; mi < 4; mi++)
    #pragma unroll
    for (int ni = 0; ni < 4; ni++){
      int gm = m0 + wm * 64 + mi * 16 + rq * 4;
      int gn = n0 + wn * 64 + ni * 16 + col;
      float4_t v = acc[mi][ni];
      #pragma unroll
      for (int r = 0; r < 4; r++){
        int row = gm + r;
        if (MODE == 0){
          outF[(size_t)row * N + gn] = v[r];
        } else if (MODE == 1){
          int bb = gn >> 12, t = gn & 4095;
          nt_store_f(&outF[(size_t)bb * 4194304 + (size_t)row * 4096 + t], v[r]);
        } else if (MODE == 2){
          nt_store_u16(&outB[(size_t)row * N + gn], bf_from_f(v[r] + bias[gn]));
        } else if (MODE == 3){
          nt_store_f(&outF[(size_t)row * N + gn], v[r] + bias[gn]);
        } else {
          float val = v[r];
          u16 h = bf_from_f(val);
          outB[(size_t)row * N + gn] = h;
          outB2[(size_t)row * N + gn] = bf_from_f(val - f_from_bf(h));
        }
      }
    }
}

template<int SPLIT, int MODE>
__global__ __launch_bounds__(256) void k_gemm128(
    const u16* __restrict__ Ah, const u16* __restrict__ Al,
    const u16* __restrict__ Bh, const u16* __restrict__ Bl,
    float* __restrict__ outF, u16* __restrict__ outB, u16* __restrict__ outB2,
    const float* __restrict__ bias, int M, int N, int K)
{
  __shared__ u16 sAh[128 * 32];
  __shared__ u16 sBh[128 * 32];
  __shared__ u16 sAl[SPLIT ? 128 * 32 : 8];
  __shared__ u16 sBl[SPLIT ? 128 * 32 : 8];
  gemm_body<SPLIT, MODE>(Ah, Al, Bh, Bl, outF, outB, outB2, bias, M, N, K,
                         blockIdx.y * 128, blockIdx.x * 128, sAh, sBh, sAl, sBl);
}

// P GEMM (blocks 0..2047, split, MODE 1) + V GEMM (blocks 2048..4095, MODE 2), one launch.
// XCD-aware remap (bijective): XCD x = bx&7 owns a contiguous slice-range; the 8 tiles
// sharing one staged slice are CONSECUTIVE local blocks -> co-resident -> fetched once.
__global__ __launch_bounds__(256) void k_gemm_pv(
    const u16* __restrict__ At_hi, const u16* __restrict__ At_lo,
    const u16* __restrict__ hs_hi, const u16* __restrict__ hs_lo,
    float* __restrict__ Pt, const u16* __restrict__ WvT, u16* __restrict__ Vb,
    const float* __restrict__ bv)
{
  __shared__ u16 smem[4 * 128 * 32];
  int bx = blockIdx.x;
  if (bx < 2048){
    int x = bx & 7, j = bx >> 3;
    int n = x * 32 + (j >> 3);   // n-tile 0..255 (B = hs slices, grouped per XCD)
    int m = j & 7;               // m-tile 0..7 inner (shares the B slice)
    gemm_body<1, 1>(At_hi, At_lo, hs_hi, hs_lo, Pt, nullptr, nullptr, nullptr,
                    1024, 32768, 1024, m * 128, n * 128,
                    smem, smem + 4096, smem + 8192, smem + 12288);
  } else {
    int id = bx - 2048;
    int x = id & 7, j = id >> 3;
    int m = x * 32 + (j >> 3);   // m-tile 0..255 (A = hs slices, grouped per XCD)
    int n = j & 7;               // n-tile 0..7 inner (shares the A slice)
    gemm_body<0, 2>(hs_hi, nullptr, WvT, nullptr, nullptr, Vb, nullptr, bv,
                    32768, 1024, 1024, m * 128, n * 128,
                    smem, smem + 4096, smem + 8192, smem + 12288);
  }
}

// ---------------- FFT forward (fused radix-4 DIF, SoA + pad, scrambled-domain unpack) ----

#define FPAD(i) ((i) + ((i) >> 3))

__global__ __launch_bounds__(256) void k_fft_fwd(const float* __restrict__ Pt,
                                                 const float* __restrict__ hsT,
                                                 float* __restrict__ S){
  __shared__ float zr[4608];
  __shared__ float zi[4608];
  int tid = threadIdx.x;
  int b = blockIdx.x >> 7;
  int ch0 = (blockIdx.x & 127) * 8;
  float Gre[8], Gim[8];
  #pragma unroll
  for (int j = 0; j < 8; ++j){ Gre[j] = 0.f; Gim[j] = 0.f; }
  float g0 = 0.f, g1 = 0.f;

  for (int c = 0; c < 8; ++c){
    __syncthreads();  // previous channel's unpack reads complete before overwrite
    size_t base = ((size_t)b * 1024 + ch0 + c) * 4096;
    for (int i = tid; i < 4096; i += 256){
      zr[FPAD(i)] = Pt[base + i];
      zi[FPAD(i)] = hsT[base + i];
    }
    // 6 fused radix-4 passes == 12 radix-2 DIF stages (identical math, bit-reversed out)
    for (int h = 1024; h >= 1; h >>= 2){
      __syncthreads();
      float wsc = -3.14159265358979323846f / (float)(2 * h);
      for (int g = tid; g < 1024; g += 256){
        int lo = g & (h - 1);
        int i0 = ((g - lo) << 2) + lo;
        int j0 = FPAD(i0), j1 = FPAD(i0 + h), j2 = FPAD(i0 + 2 * h), j3 = FPAD(i0 + 3 * h);
        float x0 = zr[j0], y0 = zi[j0];
        float x1 = zr[j1], y1 = zi[j1];
        float x2 = zr[j2], y2 = zi[j2];
        float x3 = zr[j3], y3 = zi[j3];
        float s, co;
        __sincosf(wsc * (float)lo, &s, &co);
        float b0x = x0 + x2, b0y = y0 + y2;
        float t2x = x0 - x2, t2y = y0 - y2;
        float b2x = t2x * co - t2y * s, b2y = t2x * s + t2y * co;
        float b1x = x1 + x3, b1y = y1 + y3;
        float t3x = x1 - x3, t3y = y1 - y3;
        float b3x = t3x * s + t3y * co, b3y = t3y * s - t3x * co;
        float vc = co * co - s * s, vs = 2.0f * co * s;
        float d1x = b0x - b1x, d1y = b0y - b1y;
        float d3x = b2x - b3x, d3y = b2y - b3y;
        zr[j0] = b0x + b1x;            zi[j0] = b0y + b1y;
        zr[j1] = d1x * vc - d1y * vs;  zi[j1] = d1x * vs + d1y * vc;
        zr[j2] = b2x + b3x;            zi[j2] = b2y + b3y;
        zr[j3] = d3x * vc - d3y * vs;  zi[j3] = d3x * vs + d3y * vc;
      }
    }
    __syncthreads();
    // scrambled-domain Hermitian-pair unpack, G accumulated in registers.
    #pragma unroll
    for (int j = 0; j < 8; ++j){
      int idx = tid + (j << 8);
      if (idx < 2047){
        int m = idx + 1;
        int e = 31 - __clz(m);
        int p = m + (1 << e);
        int q = (3 << (e + 1)) - 1 - p;
        int ip = FPAD(p), iq = FPAD(q);
        float xa = zr[ip], ya = zi[ip];
        float xb = zr[iq], yb = zi[iq];
        Gre[j] += 0.5f * (xa * yb + ya * xb);
        Gim[j] += 0.25f * ((xa * xa + ya * ya) - (xb * xb + yb * yb));
      }
    }
    if (tid == 0){
      g0 += zr[0] * zi[0];
      g1 += zr[FPAD(1)] * zi[FPAD(1)];
    }
  }

  float* Sb = S + (size_t)b * 2049 * 2;
  #pragma unroll
  for (int j = 0; j < 8; ++j){
    int idx = tid + (j << 8);
    if (idx < 2047){
      atomicAdd(&Sb[(2 + idx) * 2], Gre[j]);
      atomicAdd(&Sb[(2 + idx) * 2 + 1], Gim[j]);
    }
  }
  if (tid == 0){ atomicAdd(&Sb[0], g0); atomicAdd(&Sb[2], g1); }
}

// inverse + top-k fused; also reduces the Sq/Sk per-wave partials (4096 each per b).
__global__ __launch_bounds__(256) void k_fft_inv_topk(const float* __restrict__ S,
    const float* __restrict__ partQ, const float* __restrict__ partK,
    const float* __restrict__ c0, float* __restrict__ tv, int* __restrict__ ti){
  __shared__ cplx z[4096];
  __shared__ float vals[4096];
  __shared__ float rv[256];
  __shared__ int ri[256];
  __shared__ float sred[8];
  int b = blockIdx.x, tid = threadIdx.x;
  // reduce Sq/Sk partials
  {
    const float* pQ = partQ + (size_t)b * 4096;
    const float* pK = partK + (size_t)b * 4096;
    float aq = 0.f, ak = 0.f;
    for (int i = tid; i < 4096; i += 256){ aq += pQ[i]; ak += pK[i]; }
    for (int o = 32; o; o >>= 1){ aq += __shfl_down(aq, o); ak += __shfl_down(ak, o); }
    if ((tid & 63) == 0){ sred[tid >> 6] = aq; sred[4 + (tid >> 6)] = ak; }
  }
  const float* Sb = S + (size_t)b * 2049 * 2;
  #pragma unroll
  for (int j = 0; j < 8; ++j){
    int idx = tid + (j << 8);
    if (idx < 2047){
      int m = idx + 1;
      int e = 31 - __clz(m);
      int p = m + (1 << e);
      int q = (3 << (e + 1)) - 1 - p;
      float re = Sb[(2 + idx) * 2], im = Sb[(2 + idx) * 2 + 1];
      z[p].x = re; z[p].y = -im;
      z[q].x = re; z[q].y = im;
    }
  }
  if (tid == 0){
    z[0].x = Sb[0]; z[0].y = -Sb[1];
    z[1].x = Sb[2]; z[1].y = -Sb[3];
  }
  // DIT radix-2: bit-reversed input -> natural output
  for (int d = 1; d <= 2048; d <<= 1){
    __syncthreads();
    for (int j = tid; j < 2048; j += 256){
      int lo = j & (d - 1);
      int i = ((j & ~(d - 1)) << 1) | lo;
      float ang = -3.14159265358979323846f * (float)lo / (float)d;
      float s, co;
      __sincosf(ang, &s, &co);
      cplx av = z[i], bv = z[i + d];
      float tx = bv.x * co - bv.y * s;
      float ty = bv.x * s + bv.y * co;
      z[i].x = av.x + tx;     z[i].y = av.y + ty;
      z[i + d].x = av.x - tx; z[i + d].y = av.y - ty;
    }
  }
  __syncthreads();
  float Sqb = sred[0] + sred[1] + sred[2] + sred[3];
  float Skb = sred[4] + sred[5] + sred[6] + sred[7];
  float constv = (Sqb + Skb + 4096.0f * c0[0]) * (1.0f / 1024.0f);
  for (int t = tid; t < 4096; t += 256)
    vals[t] = z[t].x * (1.0f / 4194304.0f) + constv;
  __syncthreads();
  // top-24
  for (int it = 0; it < 24; ++it){
    float best = -3.0e38f; int bi = 0x7fffffff;
    for (int i = tid; i < 4096; i += 256){
      float v = vals[i];
      if (v > best){ best = v; bi = i; }
    }
    rv[tid] = best; ri[tid] = bi;
    __syncthreads();
    for (int s = 128; s > 0; s >>= 1){
      if (tid < s){
        if (rv[tid + s] > rv[tid] || (rv[tid + s] == rv[tid] && ri[tid + s] < ri[tid])){
          rv[tid] = rv[tid + s]; ri[tid] = ri[tid + s];
        }
      }
      __syncthreads();
    }
    if (tid == 0){
      tv[b * 24 + it] = rv[0]; ti[b * 24 + it] = ri[0];
      vals[ri[0]] = -3.0e38f;
    }
    __syncthreads();
  }
}

// ---------------- aggregation: agg[b,t,e] = sum_k w[h%8,k] * V[b,(t+d)%T,e] ----------------
// flat grid, b = blockIdx.x & 7 (XCD affinity: each XCD touches only V[b] = 8 MB);
// 16 B loads; (w,d) pairs in registers; k-loop fully unrolled.

__global__ __launch_bounds__(256, 4) void k_aggregate(const u16* __restrict__ V,
    const float* __restrict__ tv, const int* __restrict__ ti, u16* __restrict__ agg){
  __shared__ float wv[8][24];
  __shared__ int dv[8][24];
  int tid = threadIdx.x;
  if (tid < 192){ int s = tid / 24, k = tid % 24; wv[s][k] = tv[tid]; dv[s][k] = ti[tid]; }
  __syncthreads();
  int flat = blockIdx.x;           // 2048 blocks
  int b = flat & 7;                // XCD affinity
  int t0 = (flat >> 3) * 16;
  int oct = tid & 127;             // which 8-element e-group
  int th = tid >> 7;               // t parity within the pair
  int e = oct * 8;
  int sb = (oct >> 3) & 7;         // h % 8 (h = e/64)
  const u16* Vbase = V + (size_t)b * 4194304 + e;
  u16* abase = agg + (size_t)b * 4194304 + e;

  float wk[24]; int dk[24];
  #pragma unroll
  for (int k = 0; k < 24; ++k){ wk[k] = wv[sb][k]; dk[k] = dv[sb][k]; }

  for (int tt = 0; tt < 8; ++tt){
    int t = t0 + tt * 2 + th;
    float a0 = 0, a1 = 0, a2 = 0, a3 = 0, a4 = 0, a5 = 0, a6 = 0, a7 = 0;
    #pragma unroll
    for (int k = 0; k < 24; ++k){
      int st = (t + dk[k]) & 4095;
      int4 vv = *(const int4*)(Vbase + (size_t)st * 1024);
      float w = wk[k];
      a0 += w * __uint_as_float(((unsigned)vv.x) << 16);
      a1 += w * __uint_as_float(((unsigned)vv.x) & 0xFFFF0000u);
      a2 += w * __uint_as_float(((unsigned)vv.y) << 16);
      a3 += w * __uint_as_float(((unsigned)vv.y) & 0xFFFF0000u);
      a4 += w * __uint_as_float(((unsigned)vv.z) << 16);
      a5 += w * __uint_as_float(((unsigned)vv.z) & 0xFFFF0000u);
      a6 += w * __uint_as_float(((unsigned)vv.w) << 16);
      a7 += w * __uint_as_float(((unsigned)vv.w) & 0xFFFF0000u);
    }
    int4 o;
    o.x = (int)((unsigned)bf_from_f(a0) | ((unsigned)bf_from_f(a1) << 16));
    o.y = (int)((unsigned)bf_from_f(a2) | ((unsigned)bf_from_f(a3) << 16));
    o.z = (int)((unsigned)bf_from_f(a4) | ((unsigned)bf_from_f(a5) << 16));
    o.w = (int)((unsigned)bf_from_f(a6) | ((unsigned)bf_from_f(a7) << 16));
    *(int4*)(abase + (size_t)t * 1024) = o;
  }
}

// ---------------- launch ----------------

extern "C" void kernel_launch(void* const* d_in, const int* in_sizes, int n_in,
                              void* d_out, int out_size, void* d_ws, size_t ws_size,
                              hipStream_t stream){
  const float* hs = (const float*)d_in[0];
  const float* Wq = (const float*)d_in[1];
  const float* bq = (const float*)d_in[2];
  const float* Wk = (const float*)d_in[3];
  const float* bk = (const float*)d_in[4];
  const float* Wv = (const float*)d_in[5];
  const float* bv = (const float*)d_in[6];
  const float* Wo = (const float*)d_in[7];
  const float* bo = (const float*)d_in[8];

  char* ws = (char*)d_ws;
  const size_t MB = 1024ull * 1024ull;
  u16* hs_hi = (u16*)(ws);                 // 64MB; reused as agg after P/V GEMMs
  u16* hs_lo = (u16*)(ws + 64 * MB);       // 64MB
  float* Pt  = (float*)(ws + 128 * MB);    // 128MB  [B,E,T]
  float* hsT = (float*)(ws + 256 * MB);    // 128MB  [B,E,T]
  u16* Vb    = (u16*)(ws + 384 * MB);      // 64MB bf16 [B,T,E]
  char* sm   = ws + 448 * MB;
  u16* Wq_hi = (u16*)(sm + 0 * MB);
  u16* Wq_lo = (u16*)(sm + 2 * MB);
  u16* Wk_hi = (u16*)(sm + 4 * MB);
  u16* Wk_lo = (u16*)(sm + 6 * MB);
  u16* WvT   = (u16*)(sm + 8 * MB);
  u16* WoT   = (u16*)(sm + 10 * MB);
  float* partQ = (float*)(sm + 12 * MB);   // 8 x 4096 per-wave partials (128 KB)
  float* partK = (float*)(sm + 13 * MB);   // 8 x 4096 (128 KB)
  u16* At_hi = (u16*)(sm + 16 * MB);
  u16* At_lo = (u16*)(sm + 18 * MB);
  float* S   = (float*)(sm + 20 * MB);     // 8 x 2049 pair-slots x 2 floats
  float* uu  = (float*)(sm + 22 * MB);
  float* w2  = (float*)(sm + 22 * MB + 8192);
  float* c0  = (float*)(sm + 22 * MB + 16384);
  float* tv  = (float*)(sm + 22 * MB + 17152);
  int*   ti  = (int*)(sm + 22 * MB + 18176);
  u16* agg   = hs_hi;

  hipMemsetAsync(S, 0, 8 * 2049 * 2 * sizeof(float), stream);

  k_uvc<<<513, 256, 0, stream>>>(Wq, Wk, bq, bk, uu, w2, c0);
  k_split2<<<2048, 256, 0, stream>>>(Wq, Wk, Wq_hi, Wq_lo, Wk_hi, Wk_lo);
  k_transpose2_bf16<<<dim3(32, 32, 2), dim3(32, 8), 0, stream>>>(Wv, Wo, WvT, WoT);
  k_prep_hs<<<dim3(64, 16, 8), 256, 0, stream>>>(hs, hs_hi, hs_lo, hsT, uu, w2, partQ, partK);

  // At[e,k] = sum_m Wk[e,m] * Wq[k,m], split-bf16, limbs written directly
  k_gemm128<1, 4><<<dim3(8, 8), 256, 0, stream>>>(Wk_hi, Wk_lo, Wq_hi, Wq_lo,
                                                  nullptr, At_hi, At_lo, nullptr, 1024, 1024, 1024);
  // P^T (split, MODE 1) + V (MODE 2) in one launch, XCD-aware remap
  k_gemm_pv<<<4096, 256, 0, stream>>>(At_hi, At_lo, hs_hi, hs_lo, Pt, WvT, Vb, bv);

  k_fft_fwd<<<1024, 256, 0, stream>>>(Pt, hsT, S);
  k_fft_inv_topk<<<8, 256, 0, stream>>>(S, partQ, partK, c0, tv, ti);
  k_aggregate<<<2048, 256, 0, stream>>>(Vb, tv, ti, agg);
  // out = agg @ Wo + bo (fp32 out, non-temporal)
  k_gemm128<0, 3><<<dim3(8, 256), 256, 0, stream>>>(agg, nullptr, WoT, nullptr,
                                                    (float*)d_out, nullptr, nullptr, bo, 32768, 1024, 1024);
}